// Round 1
// baseline (11663.033 us; speedup 1.0000x reference)
//
#include <hip/hip_runtime.h>
#include <hip/hip_bf16.h>
#include <math.h>

#define E_DIM 1024
#define H_NUM 16
#define D_DIM 64
#define F_DIM 4096
#define L_NUM 4
#define B_NUM 2
#define S_LEN 1024
#define V_DIM 50257
#define M_TOK 2048   // B*S

typedef __attribute__((ext_vector_type(8))) short s8v;    // 8 bf16 (4 VGPRs)
typedef __attribute__((ext_vector_type(4))) float f4v;    // 4 fp32

static __device__ __forceinline__ float bf2f(unsigned short u) {
    union { unsigned int i; float f; } c; c.i = ((unsigned int)u) << 16; return c.f;
}
static __device__ __forceinline__ unsigned short f2bf(float f) {
    union { float f; unsigned int i; } c; c.f = f;
    unsigned int r = c.i + 0x7FFFu + ((c.i >> 16) & 1u);
    return (unsigned short)(r >> 16);
}

// ---------------------------------------------------------------- embedding
__global__ void embed_kernel(const int* __restrict__ idx,
                             const float* __restrict__ tok,
                             const float* __restrict__ pos,
                             float* __restrict__ x) {
    int row = blockIdx.x;                 // b*S + s
    int s = row & (S_LEN - 1);
    int t = idx[row];
    const float* te = tok + (size_t)t * E_DIM;
    const float* pe = pos + (size_t)s * E_DIM;
    float* xr = x + (size_t)row * E_DIM;
    int c = threadIdx.x * 4;
    float4 a = *(const float4*)(te + c);
    float4 p = *(const float4*)(pe + c);
    float4 o; o.x = a.x + p.x; o.y = a.y + p.y; o.z = a.z + p.z; o.w = a.w + p.w;
    *(float4*)(xr + c) = o;
}

// ---------------------------------------------------------------- layernorm
__global__ void ln_kernel(const float* __restrict__ x,
                          const float* __restrict__ w,
                          const float* __restrict__ b,
                          ushort* __restrict__ out) {
    int row = blockIdx.x;
    const float* xr = x + (size_t)row * E_DIM;
    int tid = threadIdx.x;
    float4 v = *(const float4*)(xr + tid * 4);
    float s  = v.x + v.y + v.z + v.w;
    float s2 = v.x*v.x + v.y*v.y + v.z*v.z + v.w*v.w;
    #pragma unroll
    for (int m = 32; m >= 1; m >>= 1) {
        s  += __shfl_xor(s,  m, 64);
        s2 += __shfl_xor(s2, m, 64);
    }
    __shared__ float red[8];
    int wid = tid >> 6;
    if ((tid & 63) == 0) { red[wid] = s; red[wid + 4] = s2; }
    __syncthreads();
    s  = red[0] + red[1] + red[2] + red[3];
    s2 = red[4] + red[5] + red[6] + red[7];
    float mu  = s * (1.0f / E_DIM);
    float var = s2 * (1.0f / E_DIM) - mu * mu;
    float rs  = rsqrtf(var + 1e-5f);
    float4 wv = *(const float4*)(w + tid * 4);
    float4 bv = *(const float4*)(b + tid * 4);
    ushort4 o;
    o.x = f2bf((v.x - mu) * rs * wv.x + bv.x);
    o.y = f2bf((v.y - mu) * rs * wv.y + bv.y);
    o.z = f2bf((v.z - mu) * rs * wv.z + bv.z);
    o.w = f2bf((v.w - mu) * rs * wv.w + bv.w);
    *(ushort4*)(out + (size_t)row * E_DIM + tid * 4) = o;
}

// ---------------------------------------------------------------- attention
// one thread per (b,h,s) query row; online softmax; q/k/v bf16 [B*S][E], head h at cols h*64..
__global__ void attn_kernel(const ushort* __restrict__ q,
                            const ushort* __restrict__ k,
                            const ushort* __restrict__ v,
                            ushort* __restrict__ y) {
    int gid = blockIdx.x * 256 + threadIdx.x;   // 0..B*H*S-1
    int s  = gid & (S_LEN - 1);
    int bh = gid >> 10;
    int b = bh >> 4, h = bh & 15;
    size_t base = (size_t)b * S_LEN * E_DIM + (size_t)(h * D_DIM);
    const ushort* qp = q + base + (size_t)s * E_DIM;
    float qf[D_DIM];
    #pragma unroll
    for (int i = 0; i < 8; ++i) {
        s8v t8 = *(const s8v*)(qp + i * 8);
        #pragma unroll
        for (int j = 0; j < 8; ++j) qf[i * 8 + j] = bf2f((unsigned short)t8[j]);
    }
    float o[D_DIM];
    #pragma unroll
    for (int d = 0; d < D_DIM; ++d) o[d] = 0.f;
    float m = -1e30f, l = 0.f;
    int smax = s | 63;                    // uniform across the wave
    for (int t = 0; t <= smax; ++t) {
        const ushort* kp = k + base + (size_t)t * E_DIM;
        float sc = 0.f;
        #pragma unroll
        for (int i = 0; i < 8; ++i) {
            s8v kv = *(const s8v*)(kp + i * 8);
            #pragma unroll
            for (int j = 0; j < 8; ++j) sc += qf[i * 8 + j] * bf2f((unsigned short)kv[j]);
        }
        sc *= 0.125f;
        if (t <= s) {
            if (sc > m) {
                float corr = __expf(m - sc);
                l *= corr;
                #pragma unroll
                for (int d = 0; d < D_DIM; ++d) o[d] *= corr;
                m = sc;
            }
            float p = __expf(sc - m);
            l += p;
            const ushort* vp = v + base + (size_t)t * E_DIM;
            #pragma unroll
            for (int i = 0; i < 8; ++i) {
                s8v vv = *(const s8v*)(vp + i * 8);
                #pragma unroll
                for (int j = 0; j < 8; ++j) o[i * 8 + j] += p * bf2f((unsigned short)vv[j]);
            }
        }
    }
    float inv = 1.f / l;
    ushort* yp = y + base + (size_t)s * E_DIM;
    #pragma unroll
    for (int i = 0; i < 8; ++i) {
        s8v ov;
        #pragma unroll
        for (int j = 0; j < 8; ++j) ov[j] = (short)f2bf(o[i * 8 + j] * inv);
        *(s8v*)(yp + i * 8) = ov;
    }
}

// ---------------------------------------------------------------- GEMM
// C[M,N] = A[M,K](bf16) x B + epilogue.
// TRANS_B==1: Bsrc fp32 [K,N] (Linear weight [in,out]) -> transpose-converted into LDS.
// TRANS_B==0: Bsrc fp32 [N,K] (head_W [out,in]) -> convert into LDS directly. N-bounds handled.
// EPI: 0 = +bias -> bf16 out; 1 = +bias +residual(res fp32) -> fp32 out;
//      2 = +bias +exact GELU -> bf16 out; 3 = plain -> fp32 out (col-bounded).
template<int TRANS_B, int EPI>
__global__ __launch_bounds__(256) void gemm_kernel(
    const ushort* __restrict__ A, const float* __restrict__ Bsrc,
    const float* __restrict__ bias, const float* __restrict__ res,
    float* __restrict__ outF, ushort* __restrict__ outB,
    int Mdim, int Ndim, int Kdim)
{
    __shared__ ushort As[128][40];   // [m][k], padded row = 80B
    __shared__ ushort Bs[128][40];   // [n][k]
    int tid = threadIdx.x;
    int m0 = blockIdx.y * 128;
    int n0 = blockIdx.x * 128;
    int wid = tid >> 6, lane = tid & 63;
    int wr = wid >> 1, wc = wid & 1;
    int fr = lane & 15, fq = lane >> 4;

    f4v acc[4][4];
    #pragma unroll
    for (int mi = 0; mi < 4; ++mi)
        #pragma unroll
        for (int ni = 0; ni < 4; ++ni)
            acc[mi][ni] = (f4v){0.f, 0.f, 0.f, 0.f};

    for (int k0 = 0; k0 < Kdim; k0 += 32) {
        // ---- stage A: 128x32 bf16
        #pragma unroll
        for (int it = 0; it < 2; ++it) {
            int i = tid + it * 256;           // unit of 8 bf16
            int r = i >> 2, kk = (i & 3) << 3;
            s8v av = *(const s8v*)(A + (size_t)(m0 + r) * Kdim + k0 + kk);
            *(s8v*)(&As[r][kk]) = av;
        }
        // ---- stage B
        if (TRANS_B) {
            int kk = tid >> 3, nc = (tid & 7) << 4;
            const float* src = Bsrc + (size_t)(k0 + kk) * Ndim + n0 + nc;
            float f[16];
            #pragma unroll
            for (int j = 0; j < 4; ++j) {
                float4 t4 = *(const float4*)(src + j * 4);
                f[j*4+0] = t4.x; f[j*4+1] = t4.y; f[j*4+2] = t4.z; f[j*4+3] = t4.w;
            }
            #pragma unroll
            for (int j = 0; j < 16; ++j) Bs[nc + j][kk] = f2bf(f[j]);
        } else {
            int n = tid >> 1, kh = (tid & 1) << 4;
            s8v p0, p1;
            if (n0 + n < Ndim) {
                const float* src = Bsrc + (size_t)(n0 + n) * Kdim + k0 + kh;
                #pragma unroll
                for (int j = 0; j < 2; ++j) {
                    float4 a0 = *(const float4*)(src + j * 8);
                    float4 a1 = *(const float4*)(src + j * 8 + 4);
                    s8v pk;
                    pk[0]=(short)f2bf(a0.x); pk[1]=(short)f2bf(a0.y);
                    pk[2]=(short)f2bf(a0.z); pk[3]=(short)f2bf(a0.w);
                    pk[4]=(short)f2bf(a1.x); pk[5]=(short)f2bf(a1.y);
                    pk[6]=(short)f2bf(a1.z); pk[7]=(short)f2bf(a1.w);
                    if (j == 0) p0 = pk; else p1 = pk;
                }
            } else {
                p0 = (s8v){0,0,0,0,0,0,0,0}; p1 = p0;
            }
            *(s8v*)(&Bs[n][kh])     = p0;
            *(s8v*)(&Bs[n][kh + 8]) = p1;
        }
        __syncthreads();
        // ---- compute: 4x4 fragments of 16x16 per wave
        s8v af[4], bfv[4];
        #pragma unroll
        for (int mi = 0; mi < 4; ++mi)
            af[mi] = *(const s8v*)(&As[wr * 64 + mi * 16 + fr][fq * 8]);
        #pragma unroll
        for (int ni = 0; ni < 4; ++ni)
            bfv[ni] = *(const s8v*)(&Bs[wc * 64 + ni * 16 + fr][fq * 8]);
        #pragma unroll
        for (int mi = 0; mi < 4; ++mi)
            #pragma unroll
            for (int ni = 0; ni < 4; ++ni)
                acc[mi][ni] = __builtin_amdgcn_mfma_f32_16x16x32_bf16(
                    af[mi], bfv[ni], acc[mi][ni], 0, 0, 0);
        __syncthreads();
    }

    // ---- epilogue
    #pragma unroll
    for (int mi = 0; mi < 4; ++mi) {
        int row = m0 + wr * 64 + mi * 16 + fq * 4;
        #pragma unroll
        for (int ni = 0; ni < 4; ++ni) {
            int col = n0 + wc * 64 + ni * 16 + fr;
            float bv = 0.f;
            if (EPI == 0 || EPI == 1 || EPI == 2) bv = bias[col];
            #pragma unroll
            for (int j = 0; j < 4; ++j) {
                float val = acc[mi][ni][j] + bv;
                size_t off = (size_t)(row + j) * Ndim + col;
                if (EPI == 0) {
                    outB[off] = f2bf(val);
                } else if (EPI == 1) {
                    outF[off] = res[off] + val;
                } else if (EPI == 2) {
                    val = 0.5f * val * (1.f + erff(val * 0.70710678118654752f));
                    outB[off] = f2bf(val);
                } else {
                    if (col < Ndim) outF[off] = val;
                }
            }
        }
    }
}

// ---------------------------------------------------------------- launch
extern "C" void kernel_launch(void* const* d_in, const int* in_sizes, int n_in,
                              void* d_out, int out_size, void* d_ws, size_t ws_size,
                              hipStream_t stream) {
    (void)in_sizes; (void)n_in; (void)out_size; (void)ws_size;
    const int*   idx  = (const int*)d_in[0];
    const float* tok  = (const float*)d_in[1];
    const float* pos  = (const float*)d_in[2];
    const float* ln1w = (const float*)d_in[3];
    const float* ln1b = (const float*)d_in[4];
    const float* Wq   = (const float*)d_in[5];
    const float* bq   = (const float*)d_in[6];
    const float* Wk   = (const float*)d_in[7];
    const float* bk   = (const float*)d_in[8];
    const float* Wv   = (const float*)d_in[9];
    const float* bv   = (const float*)d_in[10];
    const float* Wo   = (const float*)d_in[11];
    const float* bo   = (const float*)d_in[12];
    const float* ln2w = (const float*)d_in[13];
    const float* ln2b = (const float*)d_in[14];
    const float* W1   = (const float*)d_in[15];
    const float* b1   = (const float*)d_in[16];
    const float* W2   = (const float*)d_in[17];
    const float* b2   = (const float*)d_in[18];
    const float* lnfw = (const float*)d_in[19];
    const float* lnfb = (const float*)d_in[20];
    const float* headW= (const float*)d_in[21];
    float* out = (float*)d_out;

    char* ws = (char*)d_ws;
    float*  x  = (float*)(ws);                              // 8 MB
    ushort* h  = (ushort*)(ws + 8u  * 1024 * 1024);         // 4 MB
    ushort* qb = (ushort*)(ws + 12u * 1024 * 1024);         // 4 MB
    ushort* kb = (ushort*)(ws + 16u * 1024 * 1024);         // 4 MB
    ushort* vb = (ushort*)(ws + 20u * 1024 * 1024);         // 4 MB
    ushort* yb = (ushort*)(ws + 24u * 1024 * 1024);         // 4 MB
    ushort* ub = (ushort*)(ws + 28u * 1024 * 1024);         // 16 MB

    dim3 blk(256);
    embed_kernel<<<dim3(M_TOK), blk, 0, stream>>>(idx, tok, pos, x);

    for (int l = 0; l < L_NUM; ++l) {
        const float* wq = Wq + (size_t)l * E_DIM * E_DIM;
        const float* wk = Wk + (size_t)l * E_DIM * E_DIM;
        const float* wv = Wv + (size_t)l * E_DIM * E_DIM;
        const float* wo = Wo + (size_t)l * E_DIM * E_DIM;
        const float* w1 = W1 + (size_t)l * E_DIM * F_DIM;
        const float* w2 = W2 + (size_t)l * F_DIM * E_DIM;

        ln_kernel<<<dim3(M_TOK), blk, 0, stream>>>(x, ln1w + l * E_DIM, ln1b + l * E_DIM, h);
        gemm_kernel<1,0><<<dim3(8,16), blk, 0, stream>>>(h, wq, bq + l*E_DIM, nullptr, nullptr, qb, M_TOK, E_DIM, E_DIM);
        gemm_kernel<1,0><<<dim3(8,16), blk, 0, stream>>>(h, wk, bk + l*E_DIM, nullptr, nullptr, kb, M_TOK, E_DIM, E_DIM);
        gemm_kernel<1,0><<<dim3(8,16), blk, 0, stream>>>(h, wv, bv + l*E_DIM, nullptr, nullptr, vb, M_TOK, E_DIM, E_DIM);
        attn_kernel<<<dim3(128), blk, 0, stream>>>(qb, kb, vb, yb);
        gemm_kernel<1,1><<<dim3(8,16), blk, 0, stream>>>(yb, wo, bo + l*E_DIM, x, x, nullptr, M_TOK, E_DIM, E_DIM);
        ln_kernel<<<dim3(M_TOK), blk, 0, stream>>>(x, ln2w + l * E_DIM, ln2b + l * E_DIM, h);
        gemm_kernel<1,2><<<dim3(32,16), blk, 0, stream>>>(h, w1, b1 + l*F_DIM, nullptr, nullptr, ub, M_TOK, F_DIM, E_DIM);
        gemm_kernel<1,1><<<dim3(8,16), blk, 0, stream>>>(ub, w2, b2 + l*E_DIM, x, x, nullptr, M_TOK, E_DIM, F_DIM);
    }

    ln_kernel<<<dim3(M_TOK), blk, 0, stream>>>(x, lnfw, lnfb, h);
    gemm_kernel<0,3><<<dim3(393,16), blk, 0, stream>>>(h, headW, nullptr, nullptr, out, nullptr, M_TOK, V_DIM, E_DIM);
}

// Round 2
// 2116.393 us; speedup vs baseline: 5.5108x; 5.5108x over previous
//
#include <hip/hip_runtime.h>
#include <hip/hip_bf16.h>
#include <math.h>

#define E_DIM 1024
#define H_NUM 16
#define D_DIM 64
#define F_DIM 4096
#define L_NUM 4
#define B_NUM 2
#define S_LEN 1024
#define V_DIM 50257
#define M_TOK 2048   // B*S

typedef __attribute__((ext_vector_type(8))) short s8v;    // 8 bf16 (4 VGPRs)
typedef __attribute__((ext_vector_type(4))) float f4v;    // 4 fp32

static __device__ __forceinline__ float bf2f(unsigned short u) {
    union { unsigned int i; float f; } c; c.i = ((unsigned int)u) << 16; return c.f;
}
static __device__ __forceinline__ unsigned short f2bf(float f) {
    union { float f; unsigned int i; } c; c.f = f;
    unsigned int r = c.i + 0x7FFFu + ((c.i >> 16) & 1u);
    return (unsigned short)(r >> 16);
}

// ---------------------------------------------------------------- embedding
__global__ void embed_kernel(const int* __restrict__ idx,
                             const float* __restrict__ tok,
                             const float* __restrict__ pos,
                             float* __restrict__ x) {
    int row = blockIdx.x;
    int s = row & (S_LEN - 1);
    int t = idx[row];
    const float* te = tok + (size_t)t * E_DIM;
    const float* pe = pos + (size_t)s * E_DIM;
    float* xr = x + (size_t)row * E_DIM;
    int c = threadIdx.x * 4;
    float4 a = *(const float4*)(te + c);
    float4 p = *(const float4*)(pe + c);
    float4 o; o.x = a.x + p.x; o.y = a.y + p.y; o.z = a.z + p.z; o.w = a.w + p.w;
    *(float4*)(xr + c) = o;
}

// ---------------------------------------------------------------- layernorm
__global__ void ln_kernel(const float* __restrict__ x,
                          const float* __restrict__ w,
                          const float* __restrict__ b,
                          ushort* __restrict__ out) {
    int row = blockIdx.x;
    const float* xr = x + (size_t)row * E_DIM;
    int tid = threadIdx.x;
    float4 v = *(const float4*)(xr + tid * 4);
    float s  = v.x + v.y + v.z + v.w;
    float s2 = v.x*v.x + v.y*v.y + v.z*v.z + v.w*v.w;
    #pragma unroll
    for (int m = 32; m >= 1; m >>= 1) {
        s  += __shfl_xor(s,  m, 64);
        s2 += __shfl_xor(s2, m, 64);
    }
    __shared__ float red[8];
    int wid = tid >> 6;
    if ((tid & 63) == 0) { red[wid] = s; red[wid + 4] = s2; }
    __syncthreads();
    s  = red[0] + red[1] + red[2] + red[3];
    s2 = red[4] + red[5] + red[6] + red[7];
    float mu  = s * (1.0f / E_DIM);
    float var = s2 * (1.0f / E_DIM) - mu * mu;
    float rs  = rsqrtf(var + 1e-5f);
    float4 wv = *(const float4*)(w + tid * 4);
    float4 bv = *(const float4*)(b + tid * 4);
    ushort4 o;
    o.x = f2bf((v.x - mu) * rs * wv.x + bv.x);
    o.y = f2bf((v.y - mu) * rs * wv.y + bv.y);
    o.z = f2bf((v.z - mu) * rs * wv.z + bv.z);
    o.w = f2bf((v.w - mu) * rs * wv.w + bv.w);
    *(ushort4*)(out + (size_t)row * E_DIM + tid * 4) = o;
}

// ---------------------------------------------------------------- MFMA flash attention
// grid: 512 blocks = 32 (b,h) x 16 q-tiles(64 rows). 4 waves/block, 16 q-rows/wave.
// K lds [t][d]; V lds transposed [d][t] (block-XOR swizzled); P per-wave lds (swizzled).
#define KSTR 72
__global__ __launch_bounds__(256) void attn_mfma_kernel(
    const ushort* __restrict__ qg, const ushort* __restrict__ kg,
    const ushort* __restrict__ vg, ushort* __restrict__ yg)
{
    __shared__ ushort Ks[64][KSTR];
    __shared__ ushort Vt[64][KSTR];
    __shared__ ushort Ps[4][16][KSTR];

    int tid = threadIdx.x;
    int wid = tid >> 6, lane = tid & 63;
    int c = lane & 15, g = lane >> 4;

    int head = blockIdx.x & 31;
    int qt = 15 - (blockIdx.x >> 5);          // heavy q-tiles dispatch first
    int b = head >> 4, h = head & 15;
    int q0 = qt * 64;
    int qw = q0 + wid * 16;
    size_t base = (size_t)b * S_LEN * E_DIM + (size_t)(h * D_DIM);

    // Q fragments in registers: A[m=q][k=d], lane holds row c, d-slab g*8 (+32*ks)
    s8v qf[2];
    #pragma unroll
    for (int ks = 0; ks < 2; ++ks)
        qf[ks] = *(const s8v*)(qg + base + (size_t)(qw + c) * E_DIM + ks * 32 + g * 8);

    f4v o[4];
    #pragma unroll
    for (int dt = 0; dt < 4; ++dt) o[dt] = (f4v){0.f, 0.f, 0.f, 0.f};
    float m[4], lsum[4];
    #pragma unroll
    for (int j = 0; j < 4; ++j) { m[j] = -1e30f; lsum[j] = 0.f; }

    for (int tt = 0; tt <= qt; ++tt) {
        int t0 = tt * 64;
        // ---- stage K [t][d] and V transposed [d][t] (swizzled)
        #pragma unroll
        for (int it = 0; it < 2; ++it) {
            int ch = tid + it * 256;           // 512 chunks of 8
            int tr = ch >> 3, dc = (ch & 7) << 3;
            s8v kv = *(const s8v*)(kg + base + (size_t)(t0 + tr) * E_DIM + dc);
            *(s8v*)(&Ks[tr][dc]) = kv;
            s8v vv = *(const s8v*)(vg + base + (size_t)(t0 + tr) * E_DIM + dc);
            int tsw = tr ^ ((ch & 7) << 3);    // XOR t-block with d-block (=ch&7)
            #pragma unroll
            for (int j = 0; j < 8; ++j)
                Vt[dc + j][tsw] = (ushort)vv[j];
        }
        __syncthreads();

        // ---- S = Q K^T  (C-layout: col=t=c, row=q=4g+j)
        f4v s4[4];
        #pragma unroll
        for (int tj = 0; tj < 4; ++tj) {
            s4[tj] = (f4v){0.f, 0.f, 0.f, 0.f};
            #pragma unroll
            for (int ks = 0; ks < 2; ++ks) {
                s8v kf = *(const s8v*)(&Ks[tj * 16 + c][ks * 32 + g * 8]);
                s4[tj] = __builtin_amdgcn_mfma_f32_16x16x32_bf16(qf[ks], kf, s4[tj], 0, 0, 0);
            }
        }

        // ---- online softmax
        bool diag = (tt == qt);
        float sc[4][4], pm[4];
        #pragma unroll
        for (int j = 0; j < 4; ++j) pm[j] = -1e30f;
        #pragma unroll
        for (int tj = 0; tj < 4; ++tj)
            #pragma unroll
            for (int j = 0; j < 4; ++j) {
                float val = s4[tj][j] * 0.125f;
                if (diag) {
                    int t_loc = tj * 16 + c;
                    int q_loc = wid * 16 + 4 * g + j;
                    if (t_loc > q_loc) val = -1e30f;
                }
                sc[tj][j] = val;
                pm[j] = fmaxf(pm[j], val);
            }
        #pragma unroll
        for (int msk = 1; msk <= 8; msk <<= 1)
            #pragma unroll
            for (int j = 0; j < 4; ++j)
                pm[j] = fmaxf(pm[j], __shfl_xor(pm[j], msk, 64));
        float rs[4], corr[4];
        #pragma unroll
        for (int j = 0; j < 4; ++j) {
            float nm = fmaxf(m[j], pm[j]);
            corr[j] = __expf(m[j] - nm);
            m[j] = nm;
            rs[j] = 0.f;
        }
        #pragma unroll
        for (int tj = 0; tj < 4; ++tj)
            #pragma unroll
            for (int j = 0; j < 4; ++j) {
                float p = __expf(sc[tj][j] - m[j]);
                rs[j] += p;
                int qloc = 4 * g + j;
                int t = tj * 16 + c;
                Ps[wid][qloc][t ^ (g << 3)] = f2bf(p);   // swizzle key = qloc>>2 = g
            }
        #pragma unroll
        for (int msk = 1; msk <= 8; msk <<= 1)
            #pragma unroll
            for (int j = 0; j < 4; ++j)
                rs[j] += __shfl_xor(rs[j], msk, 64);
        #pragma unroll
        for (int j = 0; j < 4; ++j) lsum[j] = lsum[j] * corr[j] + rs[j];
        #pragma unroll
        for (int dt = 0; dt < 4; ++dt)
            #pragma unroll
            for (int j = 0; j < 4; ++j) o[dt][j] *= corr[j];

        // ---- O += P V   (A=P from lds, B=Vt rows)
        #pragma unroll
        for (int ks = 0; ks < 2; ++ks) {
            int blk = g + 4 * ks;
            int pblk = blk ^ (c >> 2);
            s8v pa = *(const s8v*)(&Ps[wid][c][pblk << 3]);
            #pragma unroll
            for (int dt = 0; dt < 4; ++dt) {
                int d = dt * 16 + c;
                int vblk = blk ^ ((d >> 3) & 7);
                s8v vb = *(const s8v*)(&Vt[d][vblk << 3]);
                o[dt] = __builtin_amdgcn_mfma_f32_16x16x32_bf16(pa, vb, o[dt], 0, 0, 0);
            }
        }
        __syncthreads();
    }

    float inv[4];
    #pragma unroll
    for (int j = 0; j < 4; ++j) inv[j] = 1.f / lsum[j];
    #pragma unroll
    for (int dt = 0; dt < 4; ++dt)
        #pragma unroll
        for (int j = 0; j < 4; ++j)
            yg[base + (size_t)(qw + 4 * g + j) * E_DIM + dt * 16 + c] = f2bf(o[dt][j] * inv[j]);
}

// ---------------------------------------------------------------- GEMM body
// C[M,N] = A[M,K](bf16) x B + epilogue.
// TRANS_B==1: Bsrc fp32 [K,N] -> transpose-converted into LDS.
// TRANS_B==0: Bsrc fp32 [N,K] (head_W) -> convert into LDS. N-bounds handled.
// EPI: 0=+bias->bf16; 1=+bias+residual->fp32; 2=+bias+GELU->bf16; 3=plain->fp32 (col-bounded)
template<int TRANS_B, int EPI>
static __device__ __forceinline__ void gemm_body(
    const ushort* __restrict__ A, const float* __restrict__ Bsrc,
    const float* __restrict__ bias, const float* __restrict__ res,
    float* __restrict__ outF, ushort* __restrict__ outB,
    int Mdim, int Ndim, int Kdim, int bx, int by)
{
    __shared__ ushort As[128][40];
    __shared__ ushort Bs[128][40];
    int tid = threadIdx.x;
    int m0 = by * 128;
    int n0 = bx * 128;
    int wid = tid >> 6, lane = tid & 63;
    int wr = wid >> 1, wc = wid & 1;
    int fr = lane & 15, fq = lane >> 4;

    f4v acc[4][4];
    #pragma unroll
    for (int mi = 0; mi < 4; ++mi)
        #pragma unroll
        for (int ni = 0; ni < 4; ++ni)
            acc[mi][ni] = (f4v){0.f, 0.f, 0.f, 0.f};

    for (int k0 = 0; k0 < Kdim; k0 += 32) {
        #pragma unroll
        for (int it = 0; it < 2; ++it) {
            int i = tid + it * 256;
            int r = i >> 2, kk = (i & 3) << 3;
            s8v av = *(const s8v*)(A + (size_t)(m0 + r) * Kdim + k0 + kk);
            *(s8v*)(&As[r][kk]) = av;
        }
        if (TRANS_B) {
            int kk = tid >> 3, nc = (tid & 7) << 4;
            const float* src = Bsrc + (size_t)(k0 + kk) * Ndim + n0 + nc;
            float f[16];
            #pragma unroll
            for (int j = 0; j < 4; ++j) {
                float4 t4 = *(const float4*)(src + j * 4);
                f[j*4+0] = t4.x; f[j*4+1] = t4.y; f[j*4+2] = t4.z; f[j*4+3] = t4.w;
            }
            #pragma unroll
            for (int j = 0; j < 16; ++j) Bs[nc + j][kk] = f2bf(f[j]);
        } else {
            int n = tid >> 1, kh = (tid & 1) << 4;
            s8v p0, p1;
            if (n0 + n < Ndim) {
                const float* src = Bsrc + (size_t)(n0 + n) * Kdim + k0 + kh;
                #pragma unroll
                for (int j = 0; j < 2; ++j) {
                    float4 a0 = *(const float4*)(src + j * 8);
                    float4 a1 = *(const float4*)(src + j * 8 + 4);
                    s8v pk;
                    pk[0]=(short)f2bf(a0.x); pk[1]=(short)f2bf(a0.y);
                    pk[2]=(short)f2bf(a0.z); pk[3]=(short)f2bf(a0.w);
                    pk[4]=(short)f2bf(a1.x); pk[5]=(short)f2bf(a1.y);
                    pk[6]=(short)f2bf(a1.z); pk[7]=(short)f2bf(a1.w);
                    if (j == 0) p0 = pk; else p1 = pk;
                }
            } else {
                p0 = (s8v){0,0,0,0,0,0,0,0}; p1 = p0;
            }
            *(s8v*)(&Bs[n][kh])     = p0;
            *(s8v*)(&Bs[n][kh + 8]) = p1;
        }
        __syncthreads();
        s8v af[4], bfv[4];
        #pragma unroll
        for (int mi = 0; mi < 4; ++mi)
            af[mi] = *(const s8v*)(&As[wr * 64 + mi * 16 + fr][fq * 8]);
        #pragma unroll
        for (int ni = 0; ni < 4; ++ni)
            bfv[ni] = *(const s8v*)(&Bs[wc * 64 + ni * 16 + fr][fq * 8]);
        #pragma unroll
        for (int mi = 0; mi < 4; ++mi)
            #pragma unroll
            for (int ni = 0; ni < 4; ++ni)
                acc[mi][ni] = __builtin_amdgcn_mfma_f32_16x16x32_bf16(
                    af[mi], bfv[ni], acc[mi][ni], 0, 0, 0);
        __syncthreads();
    }

    #pragma unroll
    for (int mi = 0; mi < 4; ++mi) {
        int row = m0 + wr * 64 + mi * 16 + fq * 4;
        #pragma unroll
        for (int ni = 0; ni < 4; ++ni) {
            int col = n0 + wc * 64 + ni * 16 + fr;
            float bv = 0.f;
            if (EPI == 0 || EPI == 1 || EPI == 2) bv = bias[col];
            #pragma unroll
            for (int j = 0; j < 4; ++j) {
                float val = acc[mi][ni][j] + bv;
                size_t off = (size_t)(row + j) * Ndim + col;
                if (EPI == 0) {
                    outB[off] = f2bf(val);
                } else if (EPI == 1) {
                    outF[off] = res[off] + val;
                } else if (EPI == 2) {
                    val = 0.5f * val * (1.f + erff(val * 0.70710678118654752f));
                    outB[off] = f2bf(val);
                } else {
                    if (col < Ndim) outF[off] = val;
                }
            }
        }
    }
}

template<int TRANS_B, int EPI>
__global__ __launch_bounds__(256) void gemm_kernel(
    const ushort* __restrict__ A, const float* __restrict__ Bsrc,
    const float* __restrict__ bias, const float* __restrict__ res,
    float* __restrict__ outF, ushort* __restrict__ outB,
    int Mdim, int Ndim, int Kdim)
{
    gemm_body<TRANS_B, EPI>(A, Bsrc, bias, res, outF, outB, Mdim, Ndim, Kdim,
                            blockIdx.x, blockIdx.y);
}

// fused Q/K/V projection: grid (24,16); x-blocks 0-7 -> Q, 8-15 -> K, 16-23 -> V
__global__ __launch_bounds__(256) void gemm_qkv_kernel(
    const ushort* __restrict__ A,
    const float* __restrict__ Wq, const float* __restrict__ Wk, const float* __restrict__ Wv,
    const float* __restrict__ bq, const float* __restrict__ bk, const float* __restrict__ bv,
    ushort* __restrict__ oq, ushort* __restrict__ ok, ushort* __restrict__ ov)
{
    int sel = blockIdx.x >> 3;
    const float* Bsrc = (sel == 0) ? Wq : (sel == 1) ? Wk : Wv;
    const float* bias = (sel == 0) ? bq : (sel == 1) ? bk : bv;
    ushort* outB      = (sel == 0) ? oq : (sel == 1) ? ok : ov;
    gemm_body<1, 0>(A, Bsrc, bias, nullptr, nullptr, outB,
                    M_TOK, E_DIM, E_DIM, blockIdx.x & 7, blockIdx.y);
}

// ---------------------------------------------------------------- launch
extern "C" void kernel_launch(void* const* d_in, const int* in_sizes, int n_in,
                              void* d_out, int out_size, void* d_ws, size_t ws_size,
                              hipStream_t stream) {
    (void)in_sizes; (void)n_in; (void)out_size; (void)ws_size;
    const int*   idx  = (const int*)d_in[0];
    const float* tok  = (const float*)d_in[1];
    const float* pos  = (const float*)d_in[2];
    const float* ln1w = (const float*)d_in[3];
    const float* ln1b = (const float*)d_in[4];
    const float* Wq   = (const float*)d_in[5];
    const float* bq   = (const float*)d_in[6];
    const float* Wk   = (const float*)d_in[7];
    const float* bk   = (const float*)d_in[8];
    const float* Wv   = (const float*)d_in[9];
    const float* bv   = (const float*)d_in[10];
    const float* Wo   = (const float*)d_in[11];
    const float* bo   = (const float*)d_in[12];
    const float* ln2w = (const float*)d_in[13];
    const float* ln2b = (const float*)d_in[14];
    const float* W1   = (const float*)d_in[15];
    const float* b1   = (const float*)d_in[16];
    const float* W2   = (const float*)d_in[17];
    const float* b2   = (const float*)d_in[18];
    const float* lnfw = (const float*)d_in[19];
    const float* lnfb = (const float*)d_in[20];
    const float* headW= (const float*)d_in[21];
    float* out = (float*)d_out;

    char* ws = (char*)d_ws;
    float*  x  = (float*)(ws);                              // 8 MB
    ushort* h  = (ushort*)(ws + 8u  * 1024 * 1024);         // 4 MB
    ushort* qb = (ushort*)(ws + 12u * 1024 * 1024);         // 4 MB
    ushort* kb = (ushort*)(ws + 16u * 1024 * 1024);         // 4 MB
    ushort* vb = (ushort*)(ws + 20u * 1024 * 1024);         // 4 MB
    ushort* yb = (ushort*)(ws + 24u * 1024 * 1024);         // 4 MB
    ushort* ub = (ushort*)(ws + 28u * 1024 * 1024);         // 16 MB

    dim3 blk(256);
    embed_kernel<<<dim3(M_TOK), blk, 0, stream>>>(idx, tok, pos, x);

    for (int l = 0; l < L_NUM; ++l) {
        const float* wq = Wq + (size_t)l * E_DIM * E_DIM;
        const float* wk = Wk + (size_t)l * E_DIM * E_DIM;
        const float* wv = Wv + (size_t)l * E_DIM * E_DIM;
        const float* wo = Wo + (size_t)l * E_DIM * E_DIM;
        const float* w1 = W1 + (size_t)l * E_DIM * F_DIM;
        const float* w2 = W2 + (size_t)l * F_DIM * E_DIM;

        ln_kernel<<<dim3(M_TOK), blk, 0, stream>>>(x, ln1w + l * E_DIM, ln1b + l * E_DIM, h);
        gemm_qkv_kernel<<<dim3(24, 16), blk, 0, stream>>>(h, wq, wk, wv,
            bq + l*E_DIM, bk + l*E_DIM, bv + l*E_DIM, qb, kb, vb);
        attn_mfma_kernel<<<dim3(512), blk, 0, stream>>>(qb, kb, vb, yb);
        gemm_kernel<1,1><<<dim3(8,16), blk, 0, stream>>>(yb, wo, bo + l*E_DIM, x, x, nullptr, M_TOK, E_DIM, E_DIM);
        ln_kernel<<<dim3(M_TOK), blk, 0, stream>>>(x, ln2w + l * E_DIM, ln2b + l * E_DIM, h);
        gemm_kernel<1,2><<<dim3(32,16), blk, 0, stream>>>(h, w1, b1 + l*F_DIM, nullptr, nullptr, ub, M_TOK, F_DIM, E_DIM);
        gemm_kernel<1,1><<<dim3(8,16), blk, 0, stream>>>(ub, w2, b2 + l*E_DIM, x, x, nullptr, M_TOK, E_DIM, F_DIM);
    }

    ln_kernel<<<dim3(M_TOK), blk, 0, stream>>>(x, lnfw, lnfb, h);
    gemm_kernel<0,3><<<dim3(393,16), blk, 0, stream>>>(h, headW, nullptr, nullptr, out, nullptr, M_TOK, V_DIM, E_DIM);
}

// Round 3
// 1286.381 us; speedup vs baseline: 9.0665x; 1.6452x over previous
//
#include <hip/hip_runtime.h>
#include <hip/hip_bf16.h>
#include <math.h>

#define E_DIM 1024
#define H_NUM 16
#define D_DIM 64
#define F_DIM 4096
#define L_NUM 4
#define B_NUM 2
#define S_LEN 1024
#define V_DIM 50257
#define M_TOK 2048   // B*S

typedef __attribute__((ext_vector_type(8))) short s8v;    // 8 bf16 (4 VGPRs)
typedef __attribute__((ext_vector_type(4))) float f4v;    // 4 fp32

static __device__ __forceinline__ float bf2f(unsigned short u) {
    union { unsigned int i; float f; } c; c.i = ((unsigned int)u) << 16; return c.f;
}
static __device__ __forceinline__ unsigned short f2bf(float f) {
    union { float f; unsigned int i; } c; c.f = f;
    unsigned int r = c.i + 0x7FFFu + ((c.i >> 16) & 1u);
    return (unsigned short)(r >> 16);
}

// async global->LDS, 16B per lane; dest is wave-uniform base + lane*16
static __device__ __forceinline__ void gload16(const ushort* g, ushort* l) {
    __builtin_amdgcn_global_load_lds(
        (const __attribute__((address_space(1))) unsigned int*)g,
        (__attribute__((address_space(3))) unsigned int*)l, 16, 0, 0);
}

// bijective XCD swizzle (nwg % 8 == 0): consecutive logical ids land on one XCD
static __device__ __forceinline__ int xcd_swz(int hw, int nwg) {
    int cpx = nwg >> 3;
    return (hw & 7) * cpx + (hw >> 3);
}

// ---------------------------------------------------------------- embedding
__global__ void embed_kernel(const int* __restrict__ idx,
                             const float* __restrict__ tok,
                             const float* __restrict__ pos,
                             float* __restrict__ x) {
    int row = blockIdx.x;
    int s = row & (S_LEN - 1);
    int t = idx[row];
    const float* te = tok + (size_t)t * E_DIM;
    const float* pe = pos + (size_t)s * E_DIM;
    float* xr = x + (size_t)row * E_DIM;
    int c = threadIdx.x * 4;
    float4 a = *(const float4*)(te + c);
    float4 p = *(const float4*)(pe + c);
    float4 o; o.x = a.x + p.x; o.y = a.y + p.y; o.z = a.z + p.z; o.w = a.w + p.w;
    *(float4*)(xr + c) = o;
}

// ---------------------------------------------------------------- layernorm
__global__ void ln_kernel(const float* __restrict__ x,
                          const float* __restrict__ w,
                          const float* __restrict__ b,
                          ushort* __restrict__ out) {
    int row = blockIdx.x;
    const float* xr = x + (size_t)row * E_DIM;
    int tid = threadIdx.x;
    float4 v = *(const float4*)(xr + tid * 4);
    float s  = v.x + v.y + v.z + v.w;
    float s2 = v.x*v.x + v.y*v.y + v.z*v.z + v.w*v.w;
    #pragma unroll
    for (int m = 32; m >= 1; m >>= 1) {
        s  += __shfl_xor(s,  m, 64);
        s2 += __shfl_xor(s2, m, 64);
    }
    __shared__ float red[8];
    int wid = tid >> 6;
    if ((tid & 63) == 0) { red[wid] = s; red[wid + 4] = s2; }
    __syncthreads();
    s  = red[0] + red[1] + red[2] + red[3];
    s2 = red[4] + red[5] + red[6] + red[7];
    float mu  = s * (1.0f / E_DIM);
    float var = s2 * (1.0f / E_DIM) - mu * mu;
    float rs  = rsqrtf(var + 1e-5f);
    float4 wv = *(const float4*)(w + tid * 4);
    float4 bv = *(const float4*)(b + tid * 4);
    ushort4 o;
    o.x = f2bf((v.x - mu) * rs * wv.x + bv.x);
    o.y = f2bf((v.y - mu) * rs * wv.y + bv.y);
    o.z = f2bf((v.z - mu) * rs * wv.z + bv.z);
    o.w = f2bf((v.w - mu) * rs * wv.w + bv.w);
    *(ushort4*)(out + (size_t)row * E_DIM + tid * 4) = o;
}

// ---------------------------------------------------------------- weight prep
// in [K][N] fp32 -> out [N][K] bf16
__global__ void tconv_kernel(const float* __restrict__ in, ushort* __restrict__ out,
                             int K, int N) {
    __shared__ ushort t[64][72];
    int n0 = blockIdx.x * 64, k0 = blockIdx.y * 64;
    int tid = threadIdx.x;
    int r = tid >> 4, c = (tid & 15) * 4;
    #pragma unroll
    for (int it = 0; it < 4; ++it) {
        int kl = it * 16 + r;
        float4 v = *(const float4*)(in + (size_t)(k0 + kl) * N + n0 + c);
        t[kl][c]   = f2bf(v.x); t[kl][c+1] = f2bf(v.y);
        t[kl][c+2] = f2bf(v.z); t[kl][c+3] = f2bf(v.w);
    }
    __syncthreads();
    int nl = tid >> 2, k8 = (tid & 3) * 16;
    s8v o0, o1;
    #pragma unroll
    for (int j = 0; j < 8; ++j) o0[j] = (short)t[k8 + j][nl];
    #pragma unroll
    for (int j = 0; j < 8; ++j) o1[j] = (short)t[k8 + 8 + j][nl];
    *(s8v*)(out + (size_t)(n0 + nl) * K + k0 + k8)     = o0;
    *(s8v*)(out + (size_t)(n0 + nl) * K + k0 + k8 + 8) = o1;
}

// fp32 -> bf16 elementwise (headW, already [N][K])
__global__ void conv_kernel(const float* __restrict__ in, ushort* __restrict__ out, int n) {
    int i = (blockIdx.x * 256 + threadIdx.x) * 8;
    if (i + 8 <= n) {
        float4 a = *(const float4*)(in + i);
        float4 b = *(const float4*)(in + i + 4);
        s8v o;
        o[0]=(short)f2bf(a.x); o[1]=(short)f2bf(a.y); o[2]=(short)f2bf(a.z); o[3]=(short)f2bf(a.w);
        o[4]=(short)f2bf(b.x); o[5]=(short)f2bf(b.y); o[6]=(short)f2bf(b.z); o[7]=(short)f2bf(b.w);
        *(s8v*)(out + i) = o;
    }
}

// ---------------------------------------------------------------- MFMA flash attention
#define KSTR 72
__global__ __launch_bounds__(256) void attn_mfma_kernel(
    const ushort* __restrict__ qg, const ushort* __restrict__ kg,
    const ushort* __restrict__ vg, ushort* __restrict__ yg)
{
    __shared__ ushort Ks[64][KSTR];
    __shared__ ushort Vt[64][KSTR];
    __shared__ ushort Ps[4][16][KSTR];

    int tid = threadIdx.x;
    int wid = tid >> 6, lane = tid & 63;
    int c = lane & 15, g = lane >> 4;

    int head = blockIdx.x & 31;
    int qt = 15 - (blockIdx.x >> 5);
    int b = head >> 4, h = head & 15;
    int qw = qt * 64 + wid * 16;
    size_t base = (size_t)b * S_LEN * E_DIM + (size_t)(h * D_DIM);

    s8v qf[2];
    #pragma unroll
    for (int ks = 0; ks < 2; ++ks)
        qf[ks] = *(const s8v*)(qg + base + (size_t)(qw + c) * E_DIM + ks * 32 + g * 8);

    f4v o[4];
    #pragma unroll
    for (int dt = 0; dt < 4; ++dt) o[dt] = (f4v){0.f, 0.f, 0.f, 0.f};
    float m[4], lsum[4];
    #pragma unroll
    for (int j = 0; j < 4; ++j) { m[j] = -1e30f; lsum[j] = 0.f; }

    for (int tt = 0; tt <= qt; ++tt) {
        int t0 = tt * 64;
        #pragma unroll
        for (int it = 0; it < 2; ++it) {
            int ch = tid + it * 256;
            int tr = ch >> 3, dc = (ch & 7) << 3;
            s8v kv = *(const s8v*)(kg + base + (size_t)(t0 + tr) * E_DIM + dc);
            *(s8v*)(&Ks[tr][dc]) = kv;
            s8v vv = *(const s8v*)(vg + base + (size_t)(t0 + tr) * E_DIM + dc);
            int tsw = tr ^ ((ch & 7) << 3);
            #pragma unroll
            for (int j = 0; j < 8; ++j)
                Vt[dc + j][tsw] = (ushort)vv[j];
        }
        __syncthreads();

        f4v s4[4];
        #pragma unroll
        for (int tj = 0; tj < 4; ++tj) {
            s4[tj] = (f4v){0.f, 0.f, 0.f, 0.f};
            #pragma unroll
            for (int ks = 0; ks < 2; ++ks) {
                s8v kf = *(const s8v*)(&Ks[tj * 16 + c][ks * 32 + g * 8]);
                s4[tj] = __builtin_amdgcn_mfma_f32_16x16x32_bf16(qf[ks], kf, s4[tj], 0, 0, 0);
            }
        }

        bool diag = (tt == qt);
        float sc[4][4], pm[4];
        #pragma unroll
        for (int j = 0; j < 4; ++j) pm[j] = -1e30f;
        #pragma unroll
        for (int tj = 0; tj < 4; ++tj)
            #pragma unroll
            for (int j = 0; j < 4; ++j) {
                float val = s4[tj][j] * 0.125f;
                if (diag) {
                    int t_loc = tj * 16 + c;
                    int q_loc = wid * 16 + 4 * g + j;
                    if (t_loc > q_loc) val = -1e30f;
                }
                sc[tj][j] = val;
                pm[j] = fmaxf(pm[j], val);
            }
        #pragma unroll
        for (int msk = 1; msk <= 8; msk <<= 1)
            #pragma unroll
            for (int j = 0; j < 4; ++j)
                pm[j] = fmaxf(pm[j], __shfl_xor(pm[j], msk, 64));
        float rs[4], corr[4];
        #pragma unroll
        for (int j = 0; j < 4; ++j) {
            float nm = fmaxf(m[j], pm[j]);
            corr[j] = __expf(m[j] - nm);
            m[j] = nm;
            rs[j] = 0.f;
        }
        #pragma unroll
        for (int tj = 0; tj < 4; ++tj)
            #pragma unroll
            for (int j = 0; j < 4; ++j) {
                float p = __expf(sc[tj][j] - m[j]);
                rs[j] += p;
                Ps[wid][4 * g + j][(tj * 16 + c) ^ (g << 3)] = f2bf(p);
            }
        #pragma unroll
        for (int msk = 1; msk <= 8; msk <<= 1)
            #pragma unroll
            for (int j = 0; j < 4; ++j)
                rs[j] += __shfl_xor(rs[j], msk, 64);
        #pragma unroll
        for (int j = 0; j < 4; ++j) lsum[j] = lsum[j] * corr[j] + rs[j];
        #pragma unroll
        for (int dt = 0; dt < 4; ++dt)
            #pragma unroll
            for (int j = 0; j < 4; ++j) o[dt][j] *= corr[j];

        #pragma unroll
        for (int ks = 0; ks < 2; ++ks) {
            int blk = g + 4 * ks;
            int pblk = blk ^ (c >> 2);
            s8v pa = *(const s8v*)(&Ps[wid][c][pblk << 3]);
            #pragma unroll
            for (int dt = 0; dt < 4; ++dt) {
                int d = dt * 16 + c;
                int vblk = blk ^ ((d >> 3) & 7);
                s8v vb = *(const s8v*)(&Vt[d][vblk << 3]);
                o[dt] = __builtin_amdgcn_mfma_f32_16x16x32_bf16(pa, vb, o[dt], 0, 0, 0);
            }
        }
        __syncthreads();
    }

    float inv[4];
    #pragma unroll
    for (int j = 0; j < 4; ++j) inv[j] = 1.f / lsum[j];
    #pragma unroll
    for (int dt = 0; dt < 4; ++dt)
        #pragma unroll
        for (int j = 0; j < 4; ++j)
            yg[base + (size_t)(qw + 4 * g + j) * E_DIM + dt * 16 + c] = f2bf(o[dt][j] * inv[j]);
}

// ---------------------------------------------------------------- bf16 GEMM (m97 structure)
// A [M,K] bf16, B [N,K] bf16 (row-major). 128x128 tile, BK=64, global_load_lds
// staging with both-sides XOR swizzle (linear LDS dest, inverse-swizzled source,
// swizzled ds_read). EPI: 0=+bias->bf16; 1=+bias+residual->fp32; 2=+bias+GELU->bf16;
// 3=plain->fp32 (col-bounded).
template<int EPI>
static __device__ __forceinline__ void gemm_bb_body(
    const ushort* __restrict__ A, const ushort* __restrict__ B,
    const float* __restrict__ bias, const float* __restrict__ res,
    float* __restrict__ outF, ushort* __restrict__ outB,
    int Ndim, int Kdim, int m0, int n0, int nRows)
{
    __shared__ ushort As[128 * 64];
    __shared__ ushort Bs[128 * 64];
    int tid = threadIdx.x;
    int wid = tid >> 6, lane = tid & 63;
    int wr = wid >> 1, wc = wid & 1;
    int fr = lane & 15, fq = lane >> 4;
    int lr = lane >> 3, ls = lane & 7;

    f4v acc[4][4];
    #pragma unroll
    for (int mi = 0; mi < 4; ++mi)
        #pragma unroll
        for (int ni = 0; ni < 4; ++ni)
            acc[mi][ni] = (f4v){0.f, 0.f, 0.f, 0.f};

    for (int k0 = 0; k0 < Kdim; k0 += 64) {
        // stage A and B: each wave covers 32 rows of each tile, 4 insts apiece
        #pragma unroll
        for (int it = 0; it < 4; ++it) {
            int r = wid * 32 + it * 8 + lr;          // 0..127
            int ss = ls ^ (r & 7);                    // inverse swizzle on source
            gload16(A + (size_t)(m0 + r) * Kdim + k0 + ss * 8,
                    As + r * 64 - lr * 64 - ls * 8);  // wave-uniform base
        }
        #pragma unroll
        for (int it = 0; it < 4; ++it) {
            int r = wid * 32 + it * 8 + lr;
            int ss = ls ^ (r & 7);
            int br = n0 + r; if (br >= nRows) br = nRows - 1;
            gload16(B + (size_t)br * Kdim + k0 + ss * 8,
                    Bs + r * 64 - lr * 64 - ls * 8);
        }
        __syncthreads();
        #pragma unroll
        for (int ks = 0; ks < 2; ++ks) {
            s8v af[4], bfv[4];
            #pragma unroll
            for (int mi = 0; mi < 4; ++mi) {
                int Ra = wr * 64 + mi * 16 + fr;
                int Sa = (ks * 4 + fq) ^ (fr & 7);
                af[mi] = *(const s8v*)(As + Ra * 64 + Sa * 8);
            }
            #pragma unroll
            for (int ni = 0; ni < 4; ++ni) {
                int Rb = wc * 64 + ni * 16 + fr;
                int Sb = (ks * 4 + fq) ^ (fr & 7);
                bfv[ni] = *(const s8v*)(Bs + Rb * 64 + Sb * 8);
            }
            #pragma unroll
            for (int mi = 0; mi < 4; ++mi)
                #pragma unroll
                for (int ni = 0; ni < 4; ++ni)
                    acc[mi][ni] = __builtin_amdgcn_mfma_f32_16x16x32_bf16(
                        af[mi], bfv[ni], acc[mi][ni], 0, 0, 0);
        }
        __syncthreads();
    }

    #pragma unroll
    for (int mi = 0; mi < 4; ++mi) {
        int row = m0 + wr * 64 + mi * 16 + fq * 4;
        #pragma unroll
        for (int ni = 0; ni < 4; ++ni) {
            int col = n0 + wc * 64 + ni * 16 + fr;
            float bv = 0.f;
            if (EPI == 0 || EPI == 1 || EPI == 2) bv = bias[col];
            #pragma unroll
            for (int j = 0; j < 4; ++j) {
                float val = acc[mi][ni][j] + bv;
                size_t off = (size_t)(row + j) * Ndim + col;
                if (EPI == 0) {
                    outB[off] = f2bf(val);
                } else if (EPI == 1) {
                    outF[off] = res[off] + val;
                } else if (EPI == 2) {
                    val = 0.5f * val * (1.f + erff(val * 0.70710678118654752f));
                    outB[off] = f2bf(val);
                } else {
                    if (col < Ndim) outF[off] = val;
                }
            }
        }
    }
}

// m-fast + XCD-swizzled wrapper; M fixed at 2048 (16 m-blocks)
template<int EPI>
__global__ __launch_bounds__(256) void gemm_bb_kernel(
    const ushort* __restrict__ A, const ushort* __restrict__ B,
    const float* __restrict__ bias, const float* __restrict__ res,
    float* __restrict__ outF, ushort* __restrict__ outB,
    int Ndim, int Kdim, int nRows)
{
    int lid = xcd_swz(blockIdx.x, gridDim.x);
    int mb = lid & 15, nb = lid >> 4;
    gemm_bb_body<EPI>(A, B, bias, res, outF, outB, Ndim, Kdim, mb * 128, nb * 128, nRows);
}

__global__ __launch_bounds__(256) void gemm_qkv_bb_kernel(
    const ushort* __restrict__ A,
    const ushort* __restrict__ Bq, const ushort* __restrict__ Bk, const ushort* __restrict__ Bv,
    const float* __restrict__ bq, const float* __restrict__ bk, const float* __restrict__ bv,
    ushort* __restrict__ oq, ushort* __restrict__ ok, ushort* __restrict__ ov)
{
    int lid = xcd_swz(blockIdx.x, 384);
    int sel = lid >> 7, rem = lid & 127;
    int mb = rem & 15, nb = rem >> 4;
    const ushort* B  = (sel == 0) ? Bq : (sel == 1) ? Bk : Bv;
    const float* bias = (sel == 0) ? bq : (sel == 1) ? bk : bv;
    ushort* o         = (sel == 0) ? oq : (sel == 1) ? ok : ov;
    gemm_bb_body<0>(A, B, bias, nullptr, nullptr, o, E_DIM, E_DIM, mb * 128, nb * 128, E_DIM);
}

// ---------------------------------------------------------------- legacy fp32-B GEMM (fallback)
template<int TRANS_B, int EPI>
static __device__ __forceinline__ void gemm_body(
    const ushort* __restrict__ A, const float* __restrict__ Bsrc,
    const float* __restrict__ bias, const float* __restrict__ res,
    float* __restrict__ outF, ushort* __restrict__ outB,
    int Mdim, int Ndim, int Kdim, int bx, int by)
{
    __shared__ ushort As[128][40];
    __shared__ ushort Bs[128][40];
    int tid = threadIdx.x;
    int m0 = by * 128;
    int n0 = bx * 128;
    int wid = tid >> 6, lane = tid & 63;
    int wr = wid >> 1, wc = wid & 1;
    int fr = lane & 15, fq = lane >> 4;

    f4v acc[4][4];
    #pragma unroll
    for (int mi = 0; mi < 4; ++mi)
        #pragma unroll
        for (int ni = 0; ni < 4; ++ni)
            acc[mi][ni] = (f4v){0.f, 0.f, 0.f, 0.f};

    for (int k0 = 0; k0 < Kdim; k0 += 32) {
        #pragma unroll
        for (int it = 0; it < 2; ++it) {
            int i = tid + it * 256;
            int r = i >> 2, kk = (i & 3) << 3;
            s8v av = *(const s8v*)(A + (size_t)(m0 + r) * Kdim + k0 + kk);
            *(s8v*)(&As[r][kk]) = av;
        }
        if (TRANS_B) {
            int kk = tid >> 3, nc = (tid & 7) << 4;
            const float* src = Bsrc + (size_t)(k0 + kk) * Ndim + n0 + nc;
            float f[16];
            #pragma unroll
            for (int j = 0; j < 4; ++j) {
                float4 t4 = *(const float4*)(src + j * 4);
                f[j*4+0] = t4.x; f[j*4+1] = t4.y; f[j*4+2] = t4.z; f[j*4+3] = t4.w;
            }
            #pragma unroll
            for (int j = 0; j < 16; ++j) Bs[nc + j][kk] = f2bf(f[j]);
        } else {
            int n = tid >> 1, kh = (tid & 1) << 4;
            s8v p0, p1;
            if (n0 + n < Ndim) {
                const float* src = Bsrc + (size_t)(n0 + n) * Kdim + k0 + kh;
                #pragma unroll
                for (int j = 0; j < 2; ++j) {
                    float4 a0 = *(const float4*)(src + j * 8);
                    float4 a1 = *(const float4*)(src + j * 8 + 4);
                    s8v pk;
                    pk[0]=(short)f2bf(a0.x); pk[1]=(short)f2bf(a0.y);
                    pk[2]=(short)f2bf(a0.z); pk[3]=(short)f2bf(a0.w);
                    pk[4]=(short)f2bf(a1.x); pk[5]=(short)f2bf(a1.y);
                    pk[6]=(short)f2bf(a1.z); pk[7]=(short)f2bf(a1.w);
                    if (j == 0) p0 = pk; else p1 = pk;
                }
            } else {
                p0 = (s8v){0,0,0,0,0,0,0,0}; p1 = p0;
            }
            *(s8v*)(&Bs[n][kh])     = p0;
            *(s8v*)(&Bs[n][kh + 8]) = p1;
        }
        __syncthreads();
        s8v af[4], bfv[4];
        #pragma unroll
        for (int mi = 0; mi < 4; ++mi)
            af[mi] = *(const s8v*)(&As[wr * 64 + mi * 16 + fr][fq * 8]);
        #pragma unroll
        for (int ni = 0; ni < 4; ++ni)
            bfv[ni] = *(const s8v*)(&Bs[wc * 64 + ni * 16 + fr][fq * 8]);
        #pragma unroll
        for (int mi = 0; mi < 4; ++mi)
            #pragma unroll
            for (int ni = 0; ni < 4; ++ni)
                acc[mi][ni] = __builtin_amdgcn_mfma_f32_16x16x32_bf16(
                    af[mi], bfv[ni], acc[mi][ni], 0, 0, 0);
        __syncthreads();
    }

    #pragma unroll
    for (int mi = 0; mi < 4; ++mi) {
        int row = m0 + wr * 64 + mi * 16 + fq * 4;
        #pragma unroll
        for (int ni = 0; ni < 4; ++ni) {
            int col = n0 + wc * 64 + ni * 16 + fr;
            float bv = 0.f;
            if (EPI == 0 || EPI == 1 || EPI == 2) bv = bias[col];
            #pragma unroll
            for (int j = 0; j < 4; ++j) {
                float val = acc[mi][ni][j] + bv;
                size_t off = (size_t)(row + j) * Ndim + col;
                if (EPI == 0) {
                    outB[off] = f2bf(val);
                } else if (EPI == 1) {
                    outF[off] = res[off] + val;
                } else if (EPI == 2) {
                    val = 0.5f * val * (1.f + erff(val * 0.70710678118654752f));
                    outB[off] = f2bf(val);
                } else {
                    if (col < Ndim) outF[off] = val;
                }
            }
        }
    }
}

template<int TRANS_B, int EPI>
__global__ __launch_bounds__(256) void gemm_kernel(
    const ushort* __restrict__ A, const float* __restrict__ Bsrc,
    const float* __restrict__ bias, const float* __restrict__ res,
    float* __restrict__ outF, ushort* __restrict__ outB,
    int Mdim, int Ndim, int Kdim)
{
    gemm_body<TRANS_B, EPI>(A, Bsrc, bias, res, outF, outB, Mdim, Ndim, Kdim,
                            blockIdx.x, blockIdx.y);
}

__global__ __launch_bounds__(256) void gemm_qkv_kernel(
    const ushort* __restrict__ A,
    const float* __restrict__ Wq, const float* __restrict__ Wk, const float* __restrict__ Wv,
    const float* __restrict__ bq, const float* __restrict__ bk, const float* __restrict__ bv,
    ushort* __restrict__ oq, ushort* __restrict__ ok, ushort* __restrict__ ov)
{
    int sel = blockIdx.x >> 3;
    const float* Bsrc = (sel == 0) ? Wq : (sel == 1) ? Wk : Wv;
    const float* bias = (sel == 0) ? bq : (sel == 1) ? bk : bv;
    ushort* outB      = (sel == 0) ? oq : (sel == 1) ? ok : ov;
    gemm_body<1, 0>(A, Bsrc, bias, nullptr, nullptr, outB,
                    M_TOK, E_DIM, E_DIM, blockIdx.x & 7, blockIdx.y);
}

// ---------------------------------------------------------------- launch
extern "C" void kernel_launch(void* const* d_in, const int* in_sizes, int n_in,
                              void* d_out, int out_size, void* d_ws, size_t ws_size,
                              hipStream_t stream) {
    (void)in_sizes; (void)n_in; (void)out_size;
    const int*   idx  = (const int*)d_in[0];
    const float* tok  = (const float*)d_in[1];
    const float* pos  = (const float*)d_in[2];
    const float* ln1w = (const float*)d_in[3];
    const float* ln1b = (const float*)d_in[4];
    const float* Wq   = (const float*)d_in[5];
    const float* bq   = (const float*)d_in[6];
    const float* Wk   = (const float*)d_in[7];
    const float* bk   = (const float*)d_in[8];
    const float* Wv   = (const float*)d_in[9];
    const float* bv   = (const float*)d_in[10];
    const float* Wo   = (const float*)d_in[11];
    const float* bo   = (const float*)d_in[12];
    const float* ln2w = (const float*)d_in[13];
    const float* ln2b = (const float*)d_in[14];
    const float* W1   = (const float*)d_in[15];
    const float* b1   = (const float*)d_in[16];
    const float* W2   = (const float*)d_in[17];
    const float* b2   = (const float*)d_in[18];
    const float* lnfw = (const float*)d_in[19];
    const float* lnfb = (const float*)d_in[20];
    const float* headW= (const float*)d_in[21];
    float* out = (float*)d_out;

    char* ws = (char*)d_ws;
    float*  x  = (float*)(ws);                              // 8 MB
    ushort* h  = (ushort*)(ws + 8u  * 1024 * 1024);         // 4 MB
    ushort* qb = (ushort*)(ws + 12u * 1024 * 1024);
    ushort* kb = (ushort*)(ws + 16u * 1024 * 1024);
    ushort* vb = (ushort*)(ws + 20u * 1024 * 1024);
    ushort* yb = (ushort*)(ws + 24u * 1024 * 1024);
    ushort* ub = (ushort*)(ws + 28u * 1024 * 1024);         // 16 MB
    // bf16 weight buffers (per-layer reuse)
    ushort* wqb = (ushort*)(ws + 44u * 1024 * 1024);        // 2 MB
    ushort* wkb = (ushort*)(ws + 46u * 1024 * 1024);        // 2 MB
    ushort* wvb = (ushort*)(ws + 48u * 1024 * 1024);        // 2 MB
    ushort* wob = (ushort*)(ws + 50u * 1024 * 1024);        // 2 MB
    ushort* w1b = (ushort*)(ws + 52u * 1024 * 1024);        // 8 MB
    ushort* w2b = (ushort*)(ws + 60u * 1024 * 1024);        // 8 MB
    ushort* hdb = (ushort*)(ws + 68u * 1024 * 1024);        // 98.2 MB

    size_t need_mid = 68ull * 1024 * 1024;
    size_t need_big = need_mid + (size_t)V_DIM * E_DIM * 2;
    bool mid = ws_size >= need_mid;
    bool big = ws_size >= need_big;

    dim3 blk(256);
    embed_kernel<<<dim3(M_TOK), blk, 0, stream>>>(idx, tok, pos, x);

    if (big) {
        int n = V_DIM * E_DIM;
        conv_kernel<<<dim3((n / 8 + 255) / 256), blk, 0, stream>>>(headW, hdb, n);
    }

    for (int l = 0; l < L_NUM; ++l) {
        const float* wq = Wq + (size_t)l * E_DIM * E_DIM;
        const float* wk = Wk + (size_t)l * E_DIM * E_DIM;
        const float* wv = Wv + (size_t)l * E_DIM * E_DIM;
        const float* wo = Wo + (size_t)l * E_DIM * E_DIM;
        const float* w1 = W1 + (size_t)l * E_DIM * F_DIM;
        const float* w2 = W2 + (size_t)l * F_DIM * E_DIM;

        if (mid) {
            tconv_kernel<<<dim3(16, 16), blk, 0, stream>>>(wq, wqb, E_DIM, E_DIM);
            tconv_kernel<<<dim3(16, 16), blk, 0, stream>>>(wk, wkb, E_DIM, E_DIM);
            tconv_kernel<<<dim3(16, 16), blk, 0, stream>>>(wv, wvb, E_DIM, E_DIM);
            tconv_kernel<<<dim3(16, 16), blk, 0, stream>>>(wo, wob, E_DIM, E_DIM);
            tconv_kernel<<<dim3(64, 16), blk, 0, stream>>>(w1, w1b, E_DIM, F_DIM);
            tconv_kernel<<<dim3(16, 64), blk, 0, stream>>>(w2, w2b, F_DIM, E_DIM);

            ln_kernel<<<dim3(M_TOK), blk, 0, stream>>>(x, ln1w + l * E_DIM, ln1b + l * E_DIM, h);
            gemm_qkv_bb_kernel<<<dim3(384), blk, 0, stream>>>(h, wqb, wkb, wvb,
                bq + l*E_DIM, bk + l*E_DIM, bv + l*E_DIM, qb, kb, vb);
            attn_mfma_kernel<<<dim3(512), blk, 0, stream>>>(qb, kb, vb, yb);
            gemm_bb_kernel<1><<<dim3(128), blk, 0, stream>>>(yb, wob, bo + l*E_DIM, x, x, nullptr, E_DIM, E_DIM, E_DIM);
            ln_kernel<<<dim3(M_TOK), blk, 0, stream>>>(x, ln2w + l * E_DIM, ln2b + l * E_DIM, h);
            gemm_bb_kernel<2><<<dim3(512), blk, 0, stream>>>(h, w1b, b1 + l*F_DIM, nullptr, nullptr, ub, F_DIM, E_DIM, F_DIM);
            gemm_bb_kernel<1><<<dim3(128), blk, 0, stream>>>(ub, w2b, b2 + l*E_DIM, x, x, nullptr, E_DIM, F_DIM, E_DIM);
        } else {
            ln_kernel<<<dim3(M_TOK), blk, 0, stream>>>(x, ln1w + l * E_DIM, ln1b + l * E_DIM, h);
            gemm_qkv_kernel<<<dim3(24, 16), blk, 0, stream>>>(h, wq, wk, wv,
                bq + l*E_DIM, bk + l*E_DIM, bv + l*E_DIM, qb, kb, vb);
            attn_mfma_kernel<<<dim3(512), blk, 0, stream>>>(qb, kb, vb, yb);
            gemm_kernel<1,1><<<dim3(8,16), blk, 0, stream>>>(yb, wo, bo + l*E_DIM, x, x, nullptr, M_TOK, E_DIM, E_DIM);
            ln_kernel<<<dim3(M_TOK), blk, 0, stream>>>(x, ln2w + l * E_DIM, ln2b + l * E_DIM, h);
            gemm_kernel<1,2><<<dim3(32,16), blk, 0, stream>>>(h, w1, b1 + l*F_DIM, nullptr, nullptr, ub, M_TOK, F_DIM, E_DIM);
            gemm_kernel<1,1><<<dim3(8,16), blk, 0, stream>>>(ub, w2, b2 + l*E_DIM, x, x, nullptr, M_TOK, E_DIM, F_DIM);
        }
    }

    ln_kernel<<<dim3(M_TOK), blk, 0, stream>>>(x, lnfw, lnfb, h);
    if (big) {
        gemm_bb_kernel<3><<<dim3(6288), blk, 0, stream>>>(h, hdb, nullptr, nullptr, out, nullptr, V_DIM, E_DIM, V_DIM);
    } else {
        gemm_kernel<0,3><<<dim3(393,16), blk, 0, stream>>>(h, headW, nullptr, nullptr, out, nullptr, M_TOK, V_DIM, E_DIM);
    }
}

// Round 5
// 1260.999 us; speedup vs baseline: 9.2490x; 1.0201x over previous
//
#include <hip/hip_runtime.h>
#include <hip/hip_bf16.h>
#include <math.h>

#define E_DIM 1024
#define H_NUM 16
#define D_DIM 64
#define F_DIM 4096
#define L_NUM 4
#define B_NUM 2
#define S_LEN 1024
#define V_DIM 50257
#define M_TOK 2048   // B*S

typedef __attribute__((ext_vector_type(8))) short s8v;    // 8 bf16 (4 VGPRs)
typedef __attribute__((ext_vector_type(4))) float f4v;    // 4 fp32

static __device__ __forceinline__ float bf2f(unsigned short u) {
    union { unsigned int i; float f; } c; c.i = ((unsigned int)u) << 16; return c.f;
}
static __device__ __forceinline__ unsigned short f2bf(float f) {
    union { float f; unsigned int i; } c; c.f = f;
    unsigned int r = c.i + 0x7FFFu + ((c.i >> 16) & 1u);
    return (unsigned short)(r >> 16);
}

// async global->LDS, 16B per lane; dest is wave-uniform base + lane*16
static __device__ __forceinline__ void gload16(const ushort* g, ushort* l) {
    __builtin_amdgcn_global_load_lds(
        (const __attribute__((address_space(1))) unsigned int*)g,
        (__attribute__((address_space(3))) unsigned int*)l, 16, 0, 0);
}

// ---------------------------------------------------------------- embedding
__global__ void embed_kernel(const int* __restrict__ idx,
                             const float* __restrict__ tok,
                             const float* __restrict__ pos,
                             float* __restrict__ x) {
    int row = blockIdx.x;
    int s = row & (S_LEN - 1);
    int t = idx[row];
    const float* te = tok + (size_t)t * E_DIM;
    const float* pe = pos + (size_t)s * E_DIM;
    float* xr = x + (size_t)row * E_DIM;
    int c = threadIdx.x * 4;
    float4 a = *(const float4*)(te + c);
    float4 p = *(const float4*)(pe + c);
    float4 o; o.x = a.x + p.x; o.y = a.y + p.y; o.z = a.z + p.z; o.w = a.w + p.w;
    *(float4*)(xr + c) = o;
}

// ---------------------------------------------------------------- layernorm
__global__ void ln_kernel(const float* __restrict__ x,
                          const float* __restrict__ w,
                          const float* __restrict__ b,
                          ushort* __restrict__ out) {
    int row = blockIdx.x;
    const float* xr = x + (size_t)row * E_DIM;
    int tid = threadIdx.x;
    float4 v = *(const float4*)(xr + tid * 4);
    float s  = v.x + v.y + v.z + v.w;
    float s2 = v.x*v.x + v.y*v.y + v.z*v.z + v.w*v.w;
    #pragma unroll
    for (int m = 32; m >= 1; m >>= 1) {
        s  += __shfl_xor(s,  m, 64);
        s2 += __shfl_xor(s2, m, 64);
    }
    __shared__ float red[8];
    int wid = tid >> 6;
    if ((tid & 63) == 0) { red[wid] = s; red[wid + 4] = s2; }
    __syncthreads();
    s  = red[0] + red[1] + red[2] + red[3];
    s2 = red[4] + red[5] + red[6] + red[7];
    float mu  = s * (1.0f / E_DIM);
    float var = s2 * (1.0f / E_DIM) - mu * mu;
    float rs  = rsqrtf(var + 1e-5f);
    float4 wv = *(const float4*)(w + tid * 4);
    float4 bv = *(const float4*)(b + tid * 4);
    ushort4 o;
    o.x = f2bf((v.x - mu) * rs * wv.x + bv.x);
    o.y = f2bf((v.y - mu) * rs * wv.y + bv.y);
    o.z = f2bf((v.z - mu) * rs * wv.z + bv.z);
    o.w = f2bf((v.w - mu) * rs * wv.w + bv.w);
    *(ushort4*)(out + (size_t)row * E_DIM + tid * 4) = o;
}

// ---------------------------------------------------------------- weight prep
// in [K][N] fp32 -> out [N][K] bf16
__global__ void tconv_kernel(const float* __restrict__ in, ushort* __restrict__ out,
                             int K, int N) {
    __shared__ ushort t[64][72];
    int n0 = blockIdx.x * 64, k0 = blockIdx.y * 64;
    int tid = threadIdx.x;
    int r = tid >> 4, c = (tid & 15) * 4;
    #pragma unroll
    for (int it = 0; it < 4; ++it) {
        int kl = it * 16 + r;
        float4 v = *(const float4*)(in + (size_t)(k0 + kl) * N + n0 + c);
        t[kl][c]   = f2bf(v.x); t[kl][c+1] = f2bf(v.y);
        t[kl][c+2] = f2bf(v.z); t[kl][c+3] = f2bf(v.w);
    }
    __syncthreads();
    int nl = tid >> 2, k8 = (tid & 3) * 16;
    s8v o0, o1;
    #pragma unroll
    for (int j = 0; j < 8; ++j) o0[j] = (short)t[k8 + j][nl];
    #pragma unroll
    for (int j = 0; j < 8; ++j) o1[j] = (short)t[k8 + 8 + j][nl];
    *(s8v*)(out + (size_t)(n0 + nl) * K + k0 + k8)     = o0;
    *(s8v*)(out + (size_t)(n0 + nl) * K + k0 + k8 + 8) = o1;
}

// fp32 -> bf16 elementwise (headW, already [N][K])
__global__ void conv_kernel(const float* __restrict__ in, ushort* __restrict__ out, int n) {
    int i = (blockIdx.x * 256 + threadIdx.x) * 8;
    if (i + 8 <= n) {
        float4 a = *(const float4*)(in + i);
        float4 b = *(const float4*)(in + i + 4);
        s8v o;
        o[0]=(short)f2bf(a.x); o[1]=(short)f2bf(a.y); o[2]=(short)f2bf(a.z); o[3]=(short)f2bf(a.w);
        o[4]=(short)f2bf(b.x); o[5]=(short)f2bf(b.y); o[6]=(short)f2bf(b.z); o[7]=(short)f2bf(b.w);
        *(s8v*)(out + i) = o;
    }
}

// ---------------------------------------------------------------- MFMA flash attention
#define KSTR 72
__global__ __launch_bounds__(256) void attn_mfma_kernel(
    const ushort* __restrict__ qg, const ushort* __restrict__ kg,
    const ushort* __restrict__ vg, ushort* __restrict__ yg)
{
    __shared__ ushort Ks[64][KSTR];
    __shared__ ushort Vt[64][KSTR];
    __shared__ ushort Ps[4][16][KSTR];

    int tid = threadIdx.x;
    int wid = tid >> 6, lane = tid & 63;
    int c = lane & 15, g = lane >> 4;

    int head = blockIdx.x & 31;
    int qt = 15 - (blockIdx.x >> 5);
    int b = head >> 4, h = head & 15;
    int qw = qt * 64 + wid * 16;
    size_t base = (size_t)b * S_LEN * E_DIM + (size_t)(h * D_DIM);

    s8v qf[2];
    #pragma unroll
    for (int ks = 0; ks < 2; ++ks)
        qf[ks] = *(const s8v*)(qg + base + (size_t)(qw + c) * E_DIM + ks * 32 + g * 8);

    f4v o[4];
    #pragma unroll
    for (int dt = 0; dt < 4; ++dt) o[dt] = (f4v){0.f, 0.f, 0.f, 0.f};
    float m[4], lsum[4];
    #pragma unroll
    for (int j = 0; j < 4; ++j) { m[j] = -1e30f; lsum[j] = 0.f; }

    for (int tt = 0; tt <= qt; ++tt) {
        int t0 = tt * 64;
        #pragma unroll
        for (int it = 0; it < 2; ++it) {
            int ch = tid + it * 256;
            int tr = ch >> 3, dc = (ch & 7) << 3;
            s8v kv = *(const s8v*)(kg + base + (size_t)(t0 + tr) * E_DIM + dc);
            *(s8v*)(&Ks[tr][dc]) = kv;
            s8v vv = *(const s8v*)(vg + base + (size_t)(t0 + tr) * E_DIM + dc);
            int tsw = tr ^ ((ch & 7) << 3);
            #pragma unroll
            for (int j = 0; j < 8; ++j)
                Vt[dc + j][tsw] = (ushort)vv[j];
        }
        __syncthreads();

        f4v s4[4];
        #pragma unroll
        for (int tj = 0; tj < 4; ++tj) {
            s4[tj] = (f4v){0.f, 0.f, 0.f, 0.f};
            #pragma unroll
            for (int ks = 0; ks < 2; ++ks) {
                s8v kf = *(const s8v*)(&Ks[tj * 16 + c][ks * 32 + g * 8]);
                s4[tj] = __builtin_amdgcn_mfma_f32_16x16x32_bf16(qf[ks], kf, s4[tj], 0, 0, 0);
            }
        }

        bool diag = (tt == qt);
        float sc[4][4], pm[4];
        #pragma unroll
        for (int j = 0; j < 4; ++j) pm[j] = -1e30f;
        #pragma unroll
        for (int tj = 0; tj < 4; ++tj)
            #pragma unroll
            for (int j = 0; j < 4; ++j) {
                float val = s4[tj][j] * 0.125f;
                if (diag) {
                    int t_loc = tj * 16 + c;
                    int q_loc = wid * 16 + 4 * g + j;
                    if (t_loc > q_loc) val = -1e30f;
                }
                sc[tj][j] = val;
                pm[j] = fmaxf(pm[j], val);
            }
        #pragma unroll
        for (int msk = 1; msk <= 8; msk <<= 1)
            #pragma unroll
            for (int j = 0; j < 4; ++j)
                pm[j] = fmaxf(pm[j], __shfl_xor(pm[j], msk, 64));
        float rs[4], corr[4];
        #pragma unroll
        for (int j = 0; j < 4; ++j) {
            float nm = fmaxf(m[j], pm[j]);
            corr[j] = __expf(m[j] - nm);
            m[j] = nm;
            rs[j] = 0.f;
        }
        #pragma unroll
        for (int tj = 0; tj < 4; ++tj)
            #pragma unroll
            for (int j = 0; j < 4; ++j) {
                float p = __expf(sc[tj][j] - m[j]);
                rs[j] += p;
                Ps[wid][4 * g + j][(tj * 16 + c) ^ (g << 3)] = f2bf(p);
            }
        #pragma unroll
        for (int msk = 1; msk <= 8; msk <<= 1)
            #pragma unroll
            for (int j = 0; j < 4; ++j)
                rs[j] += __shfl_xor(rs[j], msk, 64);
        #pragma unroll
        for (int j = 0; j < 4; ++j) lsum[j] = lsum[j] * corr[j] + rs[j];
        #pragma unroll
        for (int dt = 0; dt < 4; ++dt)
            #pragma unroll
            for (int j = 0; j < 4; ++j) o[dt][j] *= corr[j];

        #pragma unroll
        for (int ks = 0; ks < 2; ++ks) {
            int blk = g + 4 * ks;
            int pblk = blk ^ (c >> 2);
            s8v pa = *(const s8v*)(&Ps[wid][c][pblk << 3]);
            #pragma unroll
            for (int dt = 0; dt < 4; ++dt) {
                int d = dt * 16 + c;
                int vblk = blk ^ ((d >> 3) & 7);
                s8v vb = *(const s8v*)(&Vt[d][vblk << 3]);
                o[dt] = __builtin_amdgcn_mfma_f32_16x16x32_bf16(pa, vb, o[dt], 0, 0, 0);
            }
        }
        __syncthreads();
    }

    float inv[4];
    #pragma unroll
    for (int j = 0; j < 4; ++j) inv[j] = 1.f / lsum[j];
    #pragma unroll
    for (int dt = 0; dt < 4; ++dt)
        #pragma unroll
        for (int j = 0; j < 4; ++j)
            yg[base + (size_t)(qw + 4 * g + j) * E_DIM + dt * 16 + c] = f2bf(o[dt][j] * inv[j]);
}

// ---------------------------------------------------------------- bf16 GEMM (m97 structure)
// A [M,K] bf16, B [N,K] bf16 (row-major). 128x128 tile, BK=64, global_load_lds
// staging with both-sides XOR swizzle. R3-proven body (scalar epilogue).
// EPI: 0=+bias->bf16; 1=+bias+residual->fp32; 2=+bias+GELU->bf16; 3=plain->fp32 (col-bounded)
template<int EPI>
static __device__ __forceinline__ void gemm_bb_body(
    const ushort* __restrict__ A, const ushort* __restrict__ B,
    const float* __restrict__ bias, const float* __restrict__ res,
    float* __restrict__ outF, ushort* __restrict__ outB,
    int Ndim, int Kdim, int m0, int n0, int nRows)
{
    __shared__ ushort As[128 * 64];
    __shared__ ushort Bs[128 * 64];
    int tid = threadIdx.x;
    int wid = tid >> 6, lane = tid & 63;
    int wr = wid >> 1, wc = wid & 1;
    int fr = lane & 15, fq = lane >> 4;
    int lr = lane >> 3, ls = lane & 7;

    f4v acc[4][4];
    #pragma unroll
    for (int mi = 0; mi < 4; ++mi)
        #pragma unroll
        for (int ni = 0; ni < 4; ++ni)
            acc[mi][ni] = (f4v){0.f, 0.f, 0.f, 0.f};

    for (int k0 = 0; k0 < Kdim; k0 += 64) {
        // stage A and B: each wave covers 32 rows of each tile, 4 insts apiece
        #pragma unroll
        for (int it = 0; it < 4; ++it) {
            int r = wid * 32 + it * 8 + lr;          // 0..127
            int ss = ls ^ (r & 7);                    // inverse swizzle on source
            gload16(A + (size_t)(m0 + r) * Kdim + k0 + ss * 8,
                    As + r * 64 - lr * 64 - ls * 8);  // wave-uniform base
        }
        #pragma unroll
        for (int it = 0; it < 4; ++it) {
            int r = wid * 32 + it * 8 + lr;
            int ss = ls ^ (r & 7);
            int br = n0 + r; if (br >= nRows) br = nRows - 1;
            gload16(B + (size_t)br * Kdim + k0 + ss * 8,
                    Bs + r * 64 - lr * 64 - ls * 8);
        }
        __syncthreads();
        #pragma unroll
        for (int ks = 0; ks < 2; ++ks) {
            s8v af[4], bfv[4];
            #pragma unroll
            for (int mi = 0; mi < 4; ++mi) {
                int Ra = wr * 64 + mi * 16 + fr;
                int Sa = (ks * 4 + fq) ^ (fr & 7);
                af[mi] = *(const s8v*)(As + Ra * 64 + Sa * 8);
            }
            #pragma unroll
            for (int ni = 0; ni < 4; ++ni) {
                int Rb = wc * 64 + ni * 16 + fr;
                int Sb = (ks * 4 + fq) ^ (fr & 7);
                bfv[ni] = *(const s8v*)(Bs + Rb * 64 + Sb * 8);
            }
            #pragma unroll
            for (int mi = 0; mi < 4; ++mi)
                #pragma unroll
                for (int ni = 0; ni < 4; ++ni)
                    acc[mi][ni] = __builtin_amdgcn_mfma_f32_16x16x32_bf16(
                        af[mi], bfv[ni], acc[mi][ni], 0, 0, 0);
        }
        __syncthreads();
    }

    #pragma unroll
    for (int mi = 0; mi < 4; ++mi) {
        int row = m0 + wr * 64 + mi * 16 + fq * 4;
        #pragma unroll
        for (int ni = 0; ni < 4; ++ni) {
            int col = n0 + wc * 64 + ni * 16 + fr;
            float bv = 0.f;
            if (EPI == 0 || EPI == 1 || EPI == 2) bv = bias[col];
            #pragma unroll
            for (int j = 0; j < 4; ++j) {
                float val = acc[mi][ni][j] + bv;
                size_t off = (size_t)(row + j) * Ndim + col;
                if (EPI == 0) {
                    outB[off] = f2bf(val);
                } else if (EPI == 1) {
                    outF[off] = res[off] + val;
                } else if (EPI == 2) {
                    val = 0.5f * val * (1.f + erff(val * 0.70710678118654752f));
                    outB[off] = f2bf(val);
                } else {
                    if (col < Ndim) outF[off] = val;
                }
            }
        }
    }
}

// XCD-resident-A mapping: XCD x = bid&7 owns m-blocks {2x,2x+1} (A slice 512KB,
// L2-resident) and streams all n-blocks (B panels L3-shared across XCDs).
// bijective for any grid = 8 * 2 * nNB. M fixed at 2048 (16 m-blocks).
template<int EPI>
__global__ __launch_bounds__(256) void gemm_bb_kernel(
    const ushort* __restrict__ A, const ushort* __restrict__ B,
    const float* __restrict__ bias, const float* __restrict__ res,
    float* __restrict__ outF, ushort* __restrict__ outB,
    int Ndim, int Kdim, int nRows)
{
    int x = blockIdx.x & 7, i = blockIdx.x >> 3;
    int mb = x * 2 + (i & 1), nb = i >> 1;
    gemm_bb_body<EPI>(A, B, bias, res, outF, outB, Ndim, Kdim, mb * 128, nb * 128, nRows);
}

// fused QKV: grid 384 = 8 XCD * 48; per XCD: 3 mats x (2m x 8n), A slice shared
__global__ __launch_bounds__(256) void gemm_qkv_bb_kernel(
    const ushort* __restrict__ A,
    const ushort* __restrict__ Bq, const ushort* __restrict__ Bk, const ushort* __restrict__ Bv,
    const float* __restrict__ bq, const float* __restrict__ bk, const float* __restrict__ bv,
    ushort* __restrict__ oq, ushort* __restrict__ ok, ushort* __restrict__ ov)
{
    int x = blockIdx.x & 7, i = blockIdx.x >> 3;   // i in 0..47
    int sel = i >> 4, j = i & 15;
    int mb = x * 2 + (j & 1), nb = j >> 1;
    const ushort* B   = (sel == 0) ? Bq : (sel == 1) ? Bk : Bv;
    const float* bias = (sel == 0) ? bq : (sel == 1) ? bk : bv;
    ushort* o         = (sel == 0) ? oq : (sel == 1) ? ok : ov;
    gemm_bb_body<0>(A, B, bias, nullptr, nullptr, o, E_DIM, E_DIM, mb * 128, nb * 128, E_DIM);
}

// ---------------------------------------------------------------- legacy fp32-B GEMM (fallback)
template<int TRANS_B, int EPI>
static __device__ __forceinline__ void gemm_body(
    const ushort* __restrict__ A, const float* __restrict__ Bsrc,
    const float* __restrict__ bias, const float* __restrict__ res,
    float* __restrict__ outF, ushort* __restrict__ outB,
    int Mdim, int Ndim, int Kdim, int bx, int by)
{
    __shared__ ushort As[128][40];
    __shared__ ushort Bs[128][40];
    int tid = threadIdx.x;
    int m0 = by * 128;
    int n0 = bx * 128;
    int wid = tid >> 6, lane = tid & 63;
    int wr = wid >> 1, wc = wid & 1;
    int fr = lane & 15, fq = lane >> 4;

    f4v acc[4][4];
    #pragma unroll
    for (int mi = 0; mi < 4; ++mi)
        #pragma unroll
        for (int ni = 0; ni < 4; ++ni)
            acc[mi][ni] = (f4v){0.f, 0.f, 0.f, 0.f};

    for (int k0 = 0; k0 < Kdim; k0 += 32) {
        #pragma unroll
        for (int it = 0; it < 2; ++it) {
            int i = tid + it * 256;
            int r = i >> 2, kk = (i & 3) << 3;
            s8v av = *(const s8v*)(A + (size_t)(m0 + r) * Kdim + k0 + kk);
            *(s8v*)(&As[r][kk]) = av;
        }
        if (TRANS_B) {
            int kk = tid >> 3, nc = (tid & 7) << 4;
            const float* src = Bsrc + (size_t)(k0 + kk) * Ndim + n0 + nc;
            float f[16];
            #pragma unroll
            for (int j = 0; j < 4; ++j) {
                float4 t4 = *(const float4*)(src + j * 4);
                f[j*4+0] = t4.x; f[j*4+1] = t4.y; f[j*4+2] = t4.z; f[j*4+3] = t4.w;
            }
            #pragma unroll
            for (int j = 0; j < 16; ++j) Bs[nc + j][kk] = f2bf(f[j]);
        } else {
            int n = tid >> 1, kh = (tid & 1) << 4;
            s8v p0, p1;
            if (n0 + n < Ndim) {
                const float* src = Bsrc + (size_t)(n0 + n) * Kdim + k0 + kh;
                #pragma unroll
                for (int j = 0; j < 2; ++j) {
                    float4 a0 = *(const float4*)(src + j * 8);
                    float4 a1 = *(const float4*)(src + j * 8 + 4);
                    s8v pk;
                    pk[0]=(short)f2bf(a0.x); pk[1]=(short)f2bf(a0.y);
                    pk[2]=(short)f2bf(a0.z); pk[3]=(short)f2bf(a0.w);
                    pk[4]=(short)f2bf(a1.x); pk[5]=(short)f2bf(a1.y);
                    pk[6]=(short)f2bf(a1.z); pk[7]=(short)f2bf(a1.w);
                    if (j == 0) p0 = pk; else p1 = pk;
                }
            } else {
                p0 = (s8v){0,0,0,0,0,0,0,0}; p1 = p0;
            }
            *(s8v*)(&Bs[n][kh])     = p0;
            *(s8v*)(&Bs[n][kh + 8]) = p1;
        }
        __syncthreads();
        s8v af[4], bfv[4];
        #pragma unroll
        for (int mi = 0; mi < 4; ++mi)
            af[mi] = *(const s8v*)(&As[wr * 64 + mi * 16 + fr][fq * 8]);
        #pragma unroll
        for (int ni = 0; ni < 4; ++ni)
            bfv[ni] = *(const s8v*)(&Bs[wc * 64 + ni * 16 + fr][fq * 8]);
        #pragma unroll
        for (int mi = 0; mi < 4; ++mi)
            #pragma unroll
            for (int ni = 0; ni < 4; ++ni)
                acc[mi][ni] = __builtin_amdgcn_mfma_f32_16x16x32_bf16(
                    af[mi], bfv[ni], acc[mi][ni], 0, 0, 0);
        __syncthreads();
    }

    #pragma unroll
    for (int mi = 0; mi < 4; ++mi) {
        int row = m0 + wr * 64 + mi * 16 + fq * 4;
        #pragma unroll
        for (int ni = 0; ni < 4; ++ni) {
            int col = n0 + wc * 64 + ni * 16 + fr;
            float bv = 0.f;
            if (EPI == 0 || EPI == 1 || EPI == 2) bv = bias[col];
            #pragma unroll
            for (int j = 0; j < 4; ++j) {
                float val = acc[mi][ni][j] + bv;
                size_t off = (size_t)(row + j) * Ndim + col;
                if (EPI == 0) {
                    outB[off] = f2bf(val);
                } else if (EPI == 1) {
                    outF[off] = res[off] + val;
                } else if (EPI == 2) {
                    val = 0.5f * val * (1.f + erff(val * 0.70710678118654752f));
                    outB[off] = f2bf(val);
                } else {
                    if (col < Ndim) outF[off] = val;
                }
            }
        }
    }
}

template<int TRANS_B, int EPI>
__global__ __launch_bounds__(256) void gemm_kernel(
    const ushort* __restrict__ A, const float* __restrict__ Bsrc,
    const float* __restrict__ bias, const float* __restrict__ res,
    float* __restrict__ outF, ushort* __restrict__ outB,
    int Mdim, int Ndim, int Kdim)
{
    gemm_body<TRANS_B, EPI>(A, Bsrc, bias, res, outF, outB, Mdim, Ndim, Kdim,
                            blockIdx.x, blockIdx.y);
}

__global__ __launch_bounds__(256) void gemm_qkv_kernel(
    const ushort* __restrict__ A,
    const float* __restrict__ Wq, const float* __restrict__ Wk, const float* __restrict__ Wv,
    const float* __restrict__ bq, const float* __restrict__ bk, const float* __restrict__ bv,
    ushort* __restrict__ oq, ushort* __restrict__ ok, ushort* __restrict__ ov)
{
    int sel = blockIdx.x >> 3;
    const float* Bsrc = (sel == 0) ? Wq : (sel == 1) ? Wk : Wv;
    const float* bias = (sel == 0) ? bq : (sel == 1) ? bk : bv;
    ushort* outB      = (sel == 0) ? oq : (sel == 1) ? ok : ov;
    gemm_body<1, 0>(A, Bsrc, bias, nullptr, nullptr, outB,
                    M_TOK, E_DIM, E_DIM, blockIdx.x & 7, blockIdx.y);
}

// ---------------------------------------------------------------- launch
extern "C" void kernel_launch(void* const* d_in, const int* in_sizes, int n_in,
                              void* d_out, int out_size, void* d_ws, size_t ws_size,
                              hipStream_t stream) {
    (void)in_sizes; (void)n_in; (void)out_size;
    const int*   idx  = (const int*)d_in[0];
    const float* tok  = (const float*)d_in[1];
    const float* pos  = (const float*)d_in[2];
    const float* ln1w = (const float*)d_in[3];
    const float* ln1b = (const float*)d_in[4];
    const float* Wq   = (const float*)d_in[5];
    const float* bq   = (const float*)d_in[6];
    const float* Wk   = (const float*)d_in[7];
    const float* bk   = (const float*)d_in[8];
    const float* Wv   = (const float*)d_in[9];
    const float* bv   = (const float*)d_in[10];
    const float* Wo   = (const float*)d_in[11];
    const float* bo   = (const float*)d_in[12];
    const float* ln2w = (const float*)d_in[13];
    const float* ln2b = (const float*)d_in[14];
    const float* W1   = (const float*)d_in[15];
    const float* b1   = (const float*)d_in[16];
    const float* W2   = (const float*)d_in[17];
    const float* b2   = (const float*)d_in[18];
    const float* lnfw = (const float*)d_in[19];
    const float* lnfb = (const float*)d_in[20];
    const float* headW= (const float*)d_in[21];
    float* out = (float*)d_out;

    char* ws = (char*)d_ws;
    float*  x  = (float*)(ws);                              // 8 MB
    ushort* h  = (ushort*)(ws + 8u  * 1024 * 1024);         // 4 MB
    ushort* qb = (ushort*)(ws + 12u * 1024 * 1024);
    ushort* kb = (ushort*)(ws + 16u * 1024 * 1024);
    ushort* vb = (ushort*)(ws + 20u * 1024 * 1024);
    ushort* yb = (ushort*)(ws + 24u * 1024 * 1024);
    ushort* ub = (ushort*)(ws + 28u * 1024 * 1024);         // 16 MB
    // bf16 weight buffers (per-layer reuse)
    ushort* wqb = (ushort*)(ws + 44u * 1024 * 1024);        // 2 MB
    ushort* wkb = (ushort*)(ws + 46u * 1024 * 1024);        // 2 MB
    ushort* wvb = (ushort*)(ws + 48u * 1024 * 1024);        // 2 MB
    ushort* wob = (ushort*)(ws + 50u * 1024 * 1024);        // 2 MB
    ushort* w1b = (ushort*)(ws + 52u * 1024 * 1024);        // 8 MB
    ushort* w2b = (ushort*)(ws + 60u * 1024 * 1024);        // 8 MB
    ushort* hdb = (ushort*)(ws + 68u * 1024 * 1024);        // 98.2 MB

    size_t need_mid = 68ull * 1024 * 1024;
    size_t need_big = need_mid + (size_t)V_DIM * E_DIM * 2;
    bool mid = ws_size >= need_mid;
    bool big = ws_size >= need_big;

    dim3 blk(256);
    embed_kernel<<<dim3(M_TOK), blk, 0, stream>>>(idx, tok, pos, x);

    if (big) {
        int n = V_DIM * E_DIM;
        conv_kernel<<<dim3((n / 8 + 255) / 256), blk, 0, stream>>>(headW, hdb, n);
    }

    for (int l = 0; l < L_NUM; ++l) {
        const float* wq = Wq + (size_t)l * E_DIM * E_DIM;
        const float* wk = Wk + (size_t)l * E_DIM * E_DIM;
        const float* wv = Wv + (size_t)l * E_DIM * E_DIM;
        const float* wo = Wo + (size_t)l * E_DIM * E_DIM;
        const float* w1 = W1 + (size_t)l * E_DIM * F_DIM;
        const float* w2 = W2 + (size_t)l * F_DIM * E_DIM;

        if (mid) {
            tconv_kernel<<<dim3(16, 16), blk, 0, stream>>>(wq, wqb, E_DIM, E_DIM);
            tconv_kernel<<<dim3(16, 16), blk, 0, stream>>>(wk, wkb, E_DIM, E_DIM);
            tconv_kernel<<<dim3(16, 16), blk, 0, stream>>>(wv, wvb, E_DIM, E_DIM);
            tconv_kernel<<<dim3(16, 16), blk, 0, stream>>>(wo, wob, E_DIM, E_DIM);
            tconv_kernel<<<dim3(64, 16), blk, 0, stream>>>(w1, w1b, E_DIM, F_DIM);
            tconv_kernel<<<dim3(16, 64), blk, 0, stream>>>(w2, w2b, F_DIM, E_DIM);

            ln_kernel<<<dim3(M_TOK), blk, 0, stream>>>(x, ln1w + l * E_DIM, ln1b + l * E_DIM, h);
            gemm_qkv_bb_kernel<<<dim3(384), blk, 0, stream>>>(h, wqb, wkb, wvb,
                bq + l*E_DIM, bk + l*E_DIM, bv + l*E_DIM, qb, kb, vb);
            attn_mfma_kernel<<<dim3(512), blk, 0, stream>>>(qb, kb, vb, yb);
            gemm_bb_kernel<1><<<dim3(128), blk, 0, stream>>>(yb, wob, bo + l*E_DIM, x, x, nullptr, E_DIM, E_DIM, E_DIM);
            ln_kernel<<<dim3(M_TOK), blk, 0, stream>>>(x, ln2w + l * E_DIM, ln2b + l * E_DIM, h);
            gemm_bb_kernel<2><<<dim3(512), blk, 0, stream>>>(h, w1b, b1 + l*F_DIM, nullptr, nullptr, ub, F_DIM, E_DIM, F_DIM);
            gemm_bb_kernel<1><<<dim3(128), blk, 0, stream>>>(ub, w2b, b2 + l*E_DIM, x, x, nullptr, E_DIM, F_DIM, E_DIM);
        } else {
            ln_kernel<<<dim3(M_TOK), blk, 0, stream>>>(x, ln1w + l * E_DIM, ln1b + l * E_DIM, h);
            gemm_qkv_kernel<<<dim3(24, 16), blk, 0, stream>>>(h, wq, wk, wv,
                bq + l*E_DIM, bk + l*E_DIM, bv + l*E_DIM, qb, kb, vb);
            attn_mfma_kernel<<<dim3(512), blk, 0, stream>>>(qb, kb, vb, yb);
            gemm_kernel<1,1><<<dim3(8,16), blk, 0, stream>>>(yb, wo, bo + l*E_DIM, x, x, nullptr, M_TOK, E_DIM, E_DIM);
            ln_kernel<<<dim3(M_TOK), blk, 0, stream>>>(x, ln2w + l * E_DIM, ln2b + l * E_DIM, h);
            gemm_kernel<1,2><<<dim3(32,16), blk, 0, stream>>>(h, w1, b1 + l*F_DIM, nullptr, nullptr, ub, M_TOK, F_DIM, E_DIM);
            gemm_kernel<1,1><<<dim3(8,16), blk, 0, stream>>>(ub, w2, b2 + l*E_DIM, x, x, nullptr, M_TOK, E_DIM, F_DIM);
        }
    }

    ln_kernel<<<dim3(M_TOK), blk, 0, stream>>>(x, lnfw, lnfb, h);
    if (big) {
        gemm_bb_kernel<3><<<dim3(6288), blk, 0, stream>>>(h, hdb, nullptr, nullptr, out, nullptr, V_DIM, E_DIM, V_DIM);
    } else {
        gemm_kernel<0,3><<<dim3(393,16), blk, 0, stream>>>(h, headW, nullptr, nullptr, out, nullptr, M_TOK, V_DIM, E_DIM);
    }
}

// Round 6
// 1230.812 us; speedup vs baseline: 9.4759x; 1.0245x over previous
//
#include <hip/hip_runtime.h>
#include <hip/hip_bf16.h>
#include <math.h>

#define E_DIM 1024
#define H_NUM 16
#define D_DIM 64
#define F_DIM 4096
#define L_NUM 4
#define B_NUM 2
#define S_LEN 1024
#define V_DIM 50257
#define M_TOK 2048   // B*S

typedef __attribute__((ext_vector_type(8))) short s8v;    // 8 bf16 (4 VGPRs)
typedef __attribute__((ext_vector_type(4))) float f4v;    // 4 fp32

static __device__ __forceinline__ float bf2f(unsigned short u) {
    union { unsigned int i; float f; } c; c.i = ((unsigned int)u) << 16; return c.f;
}
static __device__ __forceinline__ unsigned short f2bf(float f) {
    union { float f; unsigned int i; } c; c.f = f;
    unsigned int r = c.i + 0x7FFFu + ((c.i >> 16) & 1u);
    return (unsigned short)(r >> 16);
}

// async global->LDS, 16B per lane; dest is wave-uniform base + lane*16
static __device__ __forceinline__ void gload16(const ushort* g, ushort* l) {
    __builtin_amdgcn_global_load_lds(
        (const __attribute__((address_space(1))) unsigned int*)g,
        (__attribute__((address_space(3))) unsigned int*)l, 16, 0, 0);
}

// ---------------------------------------------------------------- embedding
__global__ void embed_kernel(const int* __restrict__ idx,
                             const float* __restrict__ tok,
                             const float* __restrict__ pos,
                             float* __restrict__ x) {
    int row = blockIdx.x;
    int s = row & (S_LEN - 1);
    int t = idx[row];
    const float* te = tok + (size_t)t * E_DIM;
    const float* pe = pos + (size_t)s * E_DIM;
    float* xr = x + (size_t)row * E_DIM;
    int c = threadIdx.x * 4;
    float4 a = *(const float4*)(te + c);
    float4 p = *(const float4*)(pe + c);
    float4 o; o.x = a.x + p.x; o.y = a.y + p.y; o.z = a.z + p.z; o.w = a.w + p.w;
    *(float4*)(xr + c) = o;
}

// ---------------------------------------------------------------- layernorm
__global__ void ln_kernel(const float* __restrict__ x,
                          const float* __restrict__ w,
                          const float* __restrict__ b,
                          ushort* __restrict__ out) {
    int row = blockIdx.x;
    const float* xr = x + (size_t)row * E_DIM;
    int tid = threadIdx.x;
    float4 v = *(const float4*)(xr + tid * 4);
    float s  = v.x + v.y + v.z + v.w;
    float s2 = v.x*v.x + v.y*v.y + v.z*v.z + v.w*v.w;
    #pragma unroll
    for (int m = 32; m >= 1; m >>= 1) {
        s  += __shfl_xor(s,  m, 64);
        s2 += __shfl_xor(s2, m, 64);
    }
    __shared__ float red[8];
    int wid = tid >> 6;
    if ((tid & 63) == 0) { red[wid] = s; red[wid + 4] = s2; }
    __syncthreads();
    s  = red[0] + red[1] + red[2] + red[3];
    s2 = red[4] + red[5] + red[6] + red[7];
    float mu  = s * (1.0f / E_DIM);
    float var = s2 * (1.0f / E_DIM) - mu * mu;
    float rs  = rsqrtf(var + 1e-5f);
    float4 wv = *(const float4*)(w + tid * 4);
    float4 bv = *(const float4*)(b + tid * 4);
    ushort4 o;
    o.x = f2bf((v.x - mu) * rs * wv.x + bv.x);
    o.y = f2bf((v.y - mu) * rs * wv.y + bv.y);
    o.z = f2bf((v.z - mu) * rs * wv.z + bv.z);
    o.w = f2bf((v.w - mu) * rs * wv.w + bv.w);
    *(ushort4*)(out + (size_t)row * E_DIM + tid * 4) = o;
}

// ---------------------------------------------------------------- weight prep
// in [K][N] fp32 -> out [N][K] bf16 (one 64x64 tile per block)
static __device__ __forceinline__ void tconv_body(
    const float* __restrict__ in, ushort* __restrict__ out, int K, int N, int bx, int by)
{
    __shared__ ushort t[64][72];
    int n0 = bx * 64, k0 = by * 64;
    int tid = threadIdx.x;
    int r = tid >> 4, c = (tid & 15) * 4;
    #pragma unroll
    for (int it = 0; it < 4; ++it) {
        int kl = it * 16 + r;
        float4 v = *(const float4*)(in + (size_t)(k0 + kl) * N + n0 + c);
        t[kl][c]   = f2bf(v.x); t[kl][c+1] = f2bf(v.y);
        t[kl][c+2] = f2bf(v.z); t[kl][c+3] = f2bf(v.w);
    }
    __syncthreads();
    int nl = tid >> 2, k8 = (tid & 3) * 16;
    s8v o0, o1;
    #pragma unroll
    for (int j = 0; j < 8; ++j) o0[j] = (short)t[k8 + j][nl];
    #pragma unroll
    for (int j = 0; j < 8; ++j) o1[j] = (short)t[k8 + 8 + j][nl];
    *(s8v*)(out + (size_t)(n0 + nl) * K + k0 + k8)     = o0;
    *(s8v*)(out + (size_t)(n0 + nl) * K + k0 + k8 + 8) = o1;
}

__global__ __launch_bounds__(256) void tconv_kernel(const float* __restrict__ in,
                                                    ushort* __restrict__ out, int K, int N) {
    tconv_body(in, out, K, N, blockIdx.x, blockIdx.y);
}

// all q/k/v/o weights of all layers: grid (16,16,16), z = l*4+w
__global__ __launch_bounds__(256) void tconv_qkvo_all(
    const float* __restrict__ Wq, const float* __restrict__ Wk,
    const float* __restrict__ Wv, const float* __restrict__ Wo,
    ushort* __restrict__ out)
{
    int z = blockIdx.z, l = z >> 2, w = z & 3;
    const float* in = (w == 0 ? Wq : w == 1 ? Wk : w == 2 ? Wv : Wo)
                      + (size_t)l * E_DIM * E_DIM;
    tconv_body(in, out + (size_t)z * E_DIM * E_DIM, E_DIM, E_DIM, blockIdx.x, blockIdx.y);
}

// one weight family (W1 or W2) for all layers: grid (N/64, K/64, L)
__global__ __launch_bounds__(256) void tconv_w_all(
    const float* __restrict__ W, ushort* __restrict__ out, int K, int N)
{
    int l = blockIdx.z;
    tconv_body(W + (size_t)l * K * N, out + (size_t)l * K * N, K, N, blockIdx.x, blockIdx.y);
}

// fp32 -> bf16 elementwise (headW, already [N][K])
__global__ void conv_kernel(const float* __restrict__ in, ushort* __restrict__ out, int n) {
    int i = (blockIdx.x * 256 + threadIdx.x) * 8;
    if (i + 8 <= n) {
        float4 a = *(const float4*)(in + i);
        float4 b = *(const float4*)(in + i + 4);
        s8v o;
        o[0]=(short)f2bf(a.x); o[1]=(short)f2bf(a.y); o[2]=(short)f2bf(a.z); o[3]=(short)f2bf(a.w);
        o[4]=(short)f2bf(b.x); o[5]=(short)f2bf(b.y); o[6]=(short)f2bf(b.z); o[7]=(short)f2bf(b.w);
        *(s8v*)(out + i) = o;
    }
}

// ---------------------------------------------------------------- MFMA flash attention
#define KSTR 72
__global__ __launch_bounds__(256) void attn_mfma_kernel(
    const ushort* __restrict__ qg, const ushort* __restrict__ kg,
    const ushort* __restrict__ vg, ushort* __restrict__ yg)
{
    __shared__ ushort Ks[64][KSTR];
    __shared__ ushort Vt[64][KSTR];
    __shared__ ushort Ps[4][16][KSTR];

    int tid = threadIdx.x;
    int wid = tid >> 6, lane = tid & 63;
    int c = lane & 15, g = lane >> 4;

    int head = blockIdx.x & 31;
    int qt = 15 - (blockIdx.x >> 5);
    int b = head >> 4, h = head & 15;
    int qw = qt * 64 + wid * 16;
    size_t base = (size_t)b * S_LEN * E_DIM + (size_t)(h * D_DIM);

    s8v qf[2];
    #pragma unroll
    for (int ks = 0; ks < 2; ++ks)
        qf[ks] = *(const s8v*)(qg + base + (size_t)(qw + c) * E_DIM + ks * 32 + g * 8);

    f4v o[4];
    #pragma unroll
    for (int dt = 0; dt < 4; ++dt) o[dt] = (f4v){0.f, 0.f, 0.f, 0.f};
    float m[4], lsum[4];
    #pragma unroll
    for (int j = 0; j < 4; ++j) { m[j] = -1e30f; lsum[j] = 0.f; }

    for (int tt = 0; tt <= qt; ++tt) {
        int t0 = tt * 64;
        #pragma unroll
        for (int it = 0; it < 2; ++it) {
            int ch = tid + it * 256;
            int tr = ch >> 3, dc = (ch & 7) << 3;
            s8v kv = *(const s8v*)(kg + base + (size_t)(t0 + tr) * E_DIM + dc);
            *(s8v*)(&Ks[tr][dc]) = kv;
            s8v vv = *(const s8v*)(vg + base + (size_t)(t0 + tr) * E_DIM + dc);
            int tsw = tr ^ ((ch & 7) << 3);
            #pragma unroll
            for (int j = 0; j < 8; ++j)
                Vt[dc + j][tsw] = (ushort)vv[j];
        }
        __syncthreads();

        f4v s4[4];
        #pragma unroll
        for (int tj = 0; tj < 4; ++tj) {
            s4[tj] = (f4v){0.f, 0.f, 0.f, 0.f};
            #pragma unroll
            for (int ks = 0; ks < 2; ++ks) {
                s8v kf = *(const s8v*)(&Ks[tj * 16 + c][ks * 32 + g * 8]);
                s4[tj] = __builtin_amdgcn_mfma_f32_16x16x32_bf16(qf[ks], kf, s4[tj], 0, 0, 0);
            }
        }

        bool diag = (tt == qt);
        float sc[4][4], pm[4];
        #pragma unroll
        for (int j = 0; j < 4; ++j) pm[j] = -1e30f;
        #pragma unroll
        for (int tj = 0; tj < 4; ++tj)
            #pragma unroll
            for (int j = 0; j < 4; ++j) {
                float val = s4[tj][j] * 0.125f;
                if (diag) {
                    int t_loc = tj * 16 + c;
                    int q_loc = wid * 16 + 4 * g + j;
                    if (t_loc > q_loc) val = -1e30f;
                }
                sc[tj][j] = val;
                pm[j] = fmaxf(pm[j], val);
            }
        #pragma unroll
        for (int msk = 1; msk <= 8; msk <<= 1)
            #pragma unroll
            for (int j = 0; j < 4; ++j)
                pm[j] = fmaxf(pm[j], __shfl_xor(pm[j], msk, 64));
        float rs[4], corr[4];
        #pragma unroll
        for (int j = 0; j < 4; ++j) {
            float nm = fmaxf(m[j], pm[j]);
            corr[j] = __expf(m[j] - nm);
            m[j] = nm;
            rs[j] = 0.f;
        }
        #pragma unroll
        for (int tj = 0; tj < 4; ++tj)
            #pragma unroll
            for (int j = 0; j < 4; ++j) {
                float p = __expf(sc[tj][j] - m[j]);
                rs[j] += p;
                Ps[wid][4 * g + j][(tj * 16 + c) ^ (g << 3)] = f2bf(p);
            }
        #pragma unroll
        for (int msk = 1; msk <= 8; msk <<= 1)
            #pragma unroll
            for (int j = 0; j < 4; ++j)
                rs[j] += __shfl_xor(rs[j], msk, 64);
        #pragma unroll
        for (int j = 0; j < 4; ++j) lsum[j] = lsum[j] * corr[j] + rs[j];
        #pragma unroll
        for (int dt = 0; dt < 4; ++dt)
            #pragma unroll
            for (int j = 0; j < 4; ++j) o[dt][j] *= corr[j];

        #pragma unroll
        for (int ks = 0; ks < 2; ++ks) {
            int blk = g + 4 * ks;
            int pblk = blk ^ (c >> 2);
            s8v pa = *(const s8v*)(&Ps[wid][c][pblk << 3]);
            #pragma unroll
            for (int dt = 0; dt < 4; ++dt) {
                int d = dt * 16 + c;
                int vblk = blk ^ ((d >> 3) & 7);
                s8v vb = *(const s8v*)(&Vt[d][vblk << 3]);
                o[dt] = __builtin_amdgcn_mfma_f32_16x16x32_bf16(pa, vb, o[dt], 0, 0, 0);
            }
        }
        __syncthreads();
    }

    float inv[4];
    #pragma unroll
    for (int j = 0; j < 4; ++j) inv[j] = 1.f / lsum[j];
    #pragma unroll
    for (int dt = 0; dt < 4; ++dt)
        #pragma unroll
        for (int j = 0; j < 4; ++j)
            yg[base + (size_t)(qw + 4 * g + j) * E_DIM + dt * 16 + c] = f2bf(o[dt][j] * inv[j]);
}

// ---------------------------------------------------------------- bf16 GEMM 128x128 (proven)
template<int EPI>
static __device__ __forceinline__ void gemm_bb_body(
    const ushort* __restrict__ A, const ushort* __restrict__ B,
    const float* __restrict__ bias, const float* __restrict__ res,
    float* __restrict__ outF, ushort* __restrict__ outB,
    int Ndim, int Kdim, int m0, int n0, int nRows)
{
    __shared__ ushort As[128 * 64];
    __shared__ ushort Bs[128 * 64];
    int tid = threadIdx.x;
    int wid = tid >> 6, lane = tid & 63;
    int wr = wid >> 1, wc = wid & 1;
    int fr = lane & 15, fq = lane >> 4;
    int lr = lane >> 3, ls = lane & 7;

    f4v acc[4][4];
    #pragma unroll
    for (int mi = 0; mi < 4; ++mi)
        #pragma unroll
        for (int ni = 0; ni < 4; ++ni)
            acc[mi][ni] = (f4v){0.f, 0.f, 0.f, 0.f};

    for (int k0 = 0; k0 < Kdim; k0 += 64) {
        #pragma unroll
        for (int it = 0; it < 4; ++it) {
            int r = wid * 32 + it * 8 + lr;
            int ss = ls ^ (r & 7);
            gload16(A + (size_t)(m0 + r) * Kdim + k0 + ss * 8,
                    As + r * 64 - lr * 64 - ls * 8);
        }
        #pragma unroll
        for (int it = 0; it < 4; ++it) {
            int r = wid * 32 + it * 8 + lr;
            int ss = ls ^ (r & 7);
            int br = n0 + r; if (br >= nRows) br = nRows - 1;
            gload16(B + (size_t)br * Kdim + k0 + ss * 8,
                    Bs + r * 64 - lr * 64 - ls * 8);
        }
        __syncthreads();
        #pragma unroll
        for (int ks = 0; ks < 2; ++ks) {
            s8v af[4], bfv[4];
            #pragma unroll
            for (int mi = 0; mi < 4; ++mi) {
                int Ra = wr * 64 + mi * 16 + fr;
                int Sa = (ks * 4 + fq) ^ (fr & 7);
                af[mi] = *(const s8v*)(As + Ra * 64 + Sa * 8);
            }
            #pragma unroll
            for (int ni = 0; ni < 4; ++ni) {
                int Rb = wc * 64 + ni * 16 + fr;
                int Sb = (ks * 4 + fq) ^ (fr & 7);
                bfv[ni] = *(const s8v*)(Bs + Rb * 64 + Sb * 8);
            }
            #pragma unroll
            for (int mi = 0; mi < 4; ++mi)
                #pragma unroll
                for (int ni = 0; ni < 4; ++ni)
                    acc[mi][ni] = __builtin_amdgcn_mfma_f32_16x16x32_bf16(
                        af[mi], bfv[ni], acc[mi][ni], 0, 0, 0);
        }
        __syncthreads();
    }

    #pragma unroll
    for (int mi = 0; mi < 4; ++mi) {
        int row = m0 + wr * 64 + mi * 16 + fq * 4;
        #pragma unroll
        for (int ni = 0; ni < 4; ++ni) {
            int col = n0 + wc * 64 + ni * 16 + fr;
            float bv = 0.f;
            if (EPI == 0 || EPI == 1 || EPI == 2) bv = bias[col];
            #pragma unroll
            for (int j = 0; j < 4; ++j) {
                float val = acc[mi][ni][j] + bv;
                size_t off = (size_t)(row + j) * Ndim + col;
                if (EPI == 0) {
                    outB[off] = f2bf(val);
                } else if (EPI == 1) {
                    outF[off] = res[off] + val;
                } else if (EPI == 2) {
                    val = 0.5f * val * (1.f + erff(val * 0.70710678118654752f));
                    outB[off] = f2bf(val);
                } else {
                    if (col < Ndim) outF[off] = val;
                }
            }
        }
    }
}

// XCD-resident-A mapping (R5-proven): XCD x owns m-blocks {2x,2x+1}
template<int EPI>
__global__ __launch_bounds__(256) void gemm_bb_kernel(
    const ushort* __restrict__ A, const ushort* __restrict__ B,
    const float* __restrict__ bias, const float* __restrict__ res,
    float* __restrict__ outF, ushort* __restrict__ outB,
    int Ndim, int Kdim, int nRows)
{
    int x = blockIdx.x & 7, i = blockIdx.x >> 3;
    int mb = x * 2 + (i & 1), nb = i >> 1;
    gemm_bb_body<EPI>(A, B, bias, res, outF, outB, Ndim, Kdim, mb * 128, nb * 128, nRows);
}

__global__ __launch_bounds__(256) void gemm_qkv_bb_kernel(
    const ushort* __restrict__ A,
    const ushort* __restrict__ Bq, const ushort* __restrict__ Bk, const ushort* __restrict__ Bv,
    const float* __restrict__ bq, const float* __restrict__ bk, const float* __restrict__ bv,
    ushort* __restrict__ oq, ushort* __restrict__ ok, ushort* __restrict__ ov)
{
    int x = blockIdx.x & 7, i = blockIdx.x >> 3;   // i in 0..47
    int sel = i >> 4, j = i & 15;
    int mb = x * 2 + (j & 1), nb = j >> 1;
    const ushort* B   = (sel == 0) ? Bq : (sel == 1) ? Bk : Bv;
    const float* bias = (sel == 0) ? bq : (sel == 1) ? bk : bv;
    ushort* o         = (sel == 0) ? oq : (sel == 1) ? ok : ov;
    gemm_bb_body<0>(A, B, bias, nullptr, nullptr, o, E_DIM, E_DIM, mb * 128, nb * 128, E_DIM);
}

// ---------------------------------------------------------------- bf16 GEMM 64x128
// Same staging/swizzle/fragment conventions as gemm_bb_body; BM=64, 4 waves
// side-by-side in N (wave tile 64x32, acc 4x2). For grid-fill on N=1024 GEMMs.
template<int EPI>
static __device__ __forceinline__ void gemm64_body(
    const ushort* __restrict__ A, const ushort* __restrict__ B,
    const float* __restrict__ bias, const float* __restrict__ res,
    float* __restrict__ outF, ushort* __restrict__ outB,
    int Ndim, int Kdim, int m0, int n0)
{
    __shared__ ushort As[64 * 64];
    __shared__ ushort Bs[128 * 64];
    int tid = threadIdx.x;
    int wid = tid >> 6, lane = tid & 63;
    int fr = lane & 15, fq = lane >> 4;
    int lr = lane >> 3, ls = lane & 7;

    f4v acc[4][2];
    #pragma unroll
    for (int mi = 0; mi < 4; ++mi)
        #pragma unroll
        for (int ni = 0; ni < 2; ++ni)
            acc[mi][ni] = (f4v){0.f, 0.f, 0.f, 0.f};

    for (int k0 = 0; k0 < Kdim; k0 += 64) {
        #pragma unroll
        for (int it = 0; it < 2; ++it) {
            int r = wid * 16 + it * 8 + lr;          // 0..63
            int ss = ls ^ (r & 7);
            gload16(A + (size_t)(m0 + r) * Kdim + k0 + ss * 8,
                    As + r * 64 - lr * 64 - ls * 8);
        }
        #pragma unroll
        for (int it = 0; it < 4; ++it) {
            int r = wid * 32 + it * 8 + lr;          // 0..127
            int ss = ls ^ (r & 7);
            gload16(B + (size_t)(n0 + r) * Kdim + k0 + ss * 8,
                    Bs + r * 64 - lr * 64 - ls * 8);
        }
        __syncthreads();
        #pragma unroll
        for (int ks = 0; ks < 2; ++ks) {
            s8v af[4], bfv[2];
            #pragma unroll
            for (int mi = 0; mi < 4; ++mi) {
                int Ra = mi * 16 + fr;
                int Sa = (ks * 4 + fq) ^ (fr & 7);
                af[mi] = *(const s8v*)(As + Ra * 64 + Sa * 8);
            }
            #pragma unroll
            for (int ni = 0; ni < 2; ++ni) {
                int Rb = wid * 32 + ni * 16 + fr;
                int Sb = (ks * 4 + fq) ^ (fr & 7);
                bfv[ni] = *(const s8v*)(Bs + Rb * 64 + Sb * 8);
            }
            #pragma unroll
            for (int mi = 0; mi < 4; ++mi)
                #pragma unroll
                for (int ni = 0; ni < 2; ++ni)
                    acc[mi][ni] = __builtin_amdgcn_mfma_f32_16x16x32_bf16(
                        af[mi], bfv[ni], acc[mi][ni], 0, 0, 0);
        }
        __syncthreads();
    }

    #pragma unroll
    for (int mi = 0; mi < 4; ++mi) {
        int row = m0 + mi * 16 + fq * 4;
        #pragma unroll
        for (int ni = 0; ni < 2; ++ni) {
            int col = n0 + wid * 32 + ni * 16 + fr;
            float bv = bias[col];
            #pragma unroll
            for (int j = 0; j < 4; ++j) {
                float val = acc[mi][ni][j] + bv;
                size_t off = (size_t)(row + j) * Ndim + col;
                if (EPI == 0) {
                    outB[off] = f2bf(val);
                } else {
                    outF[off] = res[off] + val;
                }
            }
        }
    }
}

// Wo / W2: grid 256 = 8 XCD * 32; XCD x owns mb {4x..4x+3} (512KB A, L2-resident)
template<int EPI>
__global__ __launch_bounds__(256) void gemm64_kernel(
    const ushort* __restrict__ A, const ushort* __restrict__ B,
    const float* __restrict__ bias, const float* __restrict__ res,
    float* __restrict__ outF, ushort* __restrict__ outB,
    int Ndim, int Kdim)
{
    int x = blockIdx.x & 7, i = blockIdx.x >> 3;   // i 0..31
    int mb = x * 4 + (i & 3), nb = i >> 2;
    gemm64_body<EPI>(A, B, bias, res, outF, outB, Ndim, Kdim, mb * 64, nb * 128);
}

// fused QKV: grid 768 = 8 XCD * 96; per XCD 3 mats x (4m x 8n), shared A slice
__global__ __launch_bounds__(256) void gemm64_qkv_kernel(
    const ushort* __restrict__ A, const ushort* __restrict__ Wall,
    const float* __restrict__ bq, const float* __restrict__ bk, const float* __restrict__ bv,
    ushort* __restrict__ oq, ushort* __restrict__ ok, ushort* __restrict__ ov)
{
    int x = blockIdx.x & 7, i = blockIdx.x >> 3;   // i 0..95
    int sel = i >> 5, j = i & 31;
    int mb = x * 4 + (j & 3), nb = j >> 2;
    const ushort* B   = Wall + (size_t)sel * E_DIM * E_DIM;
    const float* bias = (sel == 0) ? bq : (sel == 1) ? bk : bv;
    ushort* o         = (sel == 0) ? oq : (sel == 1) ? ok : ov;
    gemm64_body<0>(A, B, bias, nullptr, nullptr, o, E_DIM, E_DIM, mb * 64, nb * 128);
}

// ---------------------------------------------------------------- launch
extern "C" void kernel_launch(void* const* d_in, const int* in_sizes, int n_in,
                              void* d_out, int out_size, void* d_ws, size_t ws_size,
                              hipStream_t stream) {
    (void)in_sizes; (void)n_in; (void)out_size;
    const int*   idx  = (const int*)d_in[0];
    const float* tok  = (const float*)d_in[1];
    const float* pos  = (const float*)d_in[2];
    const float* ln1w = (const float*)d_in[3];
    const float* ln1b = (const float*)d_in[4];
    const float* Wq   = (const float*)d_in[5];
    const float* bq   = (const float*)d_in[6];
    const float* Wk   = (const float*)d_in[7];
    const float* bk   = (const float*)d_in[8];
    const float* Wv   = (const float*)d_in[9];
    const float* bv   = (const float*)d_in[10];
    const float* Wo   = (const float*)d_in[11];
    const float* bo   = (const float*)d_in[12];
    const float* ln2w = (const float*)d_in[13];
    const float* ln2b = (const float*)d_in[14];
    const float* W1   = (const float*)d_in[15];
    const float* b1   = (const float*)d_in[16];
    const float* W2   = (const float*)d_in[17];
    const float* b2   = (const float*)d_in[18];
    const float* lnfw = (const float*)d_in[19];
    const float* lnfb = (const float*)d_in[20];
    const float* headW= (const float*)d_in[21];
    float* out = (float*)d_out;

    char* ws = (char*)d_ws;
    float*  x  = (float*)(ws);                              // 8 MB
    ushort* h  = (ushort*)(ws + 8u  * 1024 * 1024);         // 4 MB
    ushort* qb = (ushort*)(ws + 12u * 1024 * 1024);
    ushort* kb = (ushort*)(ws + 16u * 1024 * 1024);
    ushort* vb = (ushort*)(ws + 20u * 1024 * 1024);
    ushort* yb = (ushort*)(ws + 24u * 1024 * 1024);
    ushort* ub = (ushort*)(ws + 28u * 1024 * 1024);         // 16 MB
    // mid tier: per-layer reuse buffers
    ushort* wqb = (ushort*)(ws + 44u * 1024 * 1024);
    ushort* wkb = (ushort*)(ws + 46u * 1024 * 1024);
    ushort* wvb = (ushort*)(ws + 48u * 1024 * 1024);
    ushort* wob = (ushort*)(ws + 50u * 1024 * 1024);
    ushort* w1b = (ushort*)(ws + 52u * 1024 * 1024);
    ushort* w2b = (ushort*)(ws + 60u * 1024 * 1024);
    ushort* hdbM = (ushort*)(ws + 68u * 1024 * 1024);       // mid-tier head (98.2 MB)
    // huge tier: all weights upfront
    ushort* wall  = (ushort*)(ws + 44u  * 1024 * 1024);     // 32 MB [l*4+w][1024][1024]
    ushort* w1all = (ushort*)(ws + 76u  * 1024 * 1024);     // 32 MB
    ushort* w2all = (ushort*)(ws + 108u * 1024 * 1024);     // 32 MB
    ushort* hdbH  = (ushort*)(ws + 140u * 1024 * 1024);     // 98.2 MB

    size_t headB = (size_t)V_DIM * E_DIM * 2;
    bool huge = ws_size >= 140ull * 1024 * 1024 + headB;
    bool big  = ws_size >= 68ull * 1024 * 1024 + headB;
    bool mid  = ws_size >= 68ull * 1024 * 1024;

    dim3 blk(256);
    embed_kernel<<<dim3(M_TOK), blk, 0, stream>>>(idx, tok, pos, x);

    if (huge) {
        tconv_qkvo_all<<<dim3(16, 16, 16), blk, 0, stream>>>(Wq, Wk, Wv, Wo, wall);
        tconv_w_all<<<dim3(64, 16, 4), blk, 0, stream>>>(W1, w1all, E_DIM, F_DIM);
        tconv_w_all<<<dim3(16, 64, 4), blk, 0, stream>>>(W2, w2all, F_DIM, E_DIM);
        int n = V_DIM * E_DIM;
        conv_kernel<<<dim3((n / 8 + 255) / 256), blk, 0, stream>>>(headW, hdbH, n);

        for (int l = 0; l < L_NUM; ++l) {
            const ushort* wl  = wall  + (size_t)(l * 4) * E_DIM * E_DIM;
            const ushort* wol = wall  + (size_t)(l * 4 + 3) * E_DIM * E_DIM;
            const ushort* w1l = w1all + (size_t)l * E_DIM * F_DIM;
            const ushort* w2l = w2all + (size_t)l * F_DIM * E_DIM;

            ln_kernel<<<dim3(M_TOK), blk, 0, stream>>>(x, ln1w + l * E_DIM, ln1b + l * E_DIM, h);
            gemm64_qkv_kernel<<<dim3(768), blk, 0, stream>>>(h, wl,
                bq + l*E_DIM, bk + l*E_DIM, bv + l*E_DIM, qb, kb, vb);
            attn_mfma_kernel<<<dim3(512), blk, 0, stream>>>(qb, kb, vb, yb);
            gemm64_kernel<1><<<dim3(256), blk, 0, stream>>>(yb, wol, bo + l*E_DIM, x, x, nullptr, E_DIM, E_DIM);
            ln_kernel<<<dim3(M_TOK), blk, 0, stream>>>(x, ln2w + l * E_DIM, ln2b + l * E_DIM, h);
            gemm_bb_kernel<2><<<dim3(512), blk, 0, stream>>>(h, w1l, b1 + l*F_DIM, nullptr, nullptr, ub, F_DIM, E_DIM, F_DIM);
            gemm64_kernel<1><<<dim3(256), blk, 0, stream>>>(ub, w2l, b2 + l*E_DIM, x, x, nullptr, E_DIM, F_DIM);
        }
        ln_kernel<<<dim3(M_TOK), blk, 0, stream>>>(x, lnfw, lnfb, h);
        gemm_bb_kernel<3><<<dim3(6288), blk, 0, stream>>>(h, hdbH, nullptr, nullptr, out, nullptr, V_DIM, E_DIM, V_DIM);
        return;
    }

    if (big) {
        int n = V_DIM * E_DIM;
        conv_kernel<<<dim3((n / 8 + 255) / 256), blk, 0, stream>>>(headW, hdbM, n);
    }

    for (int l = 0; l < L_NUM; ++l) {
        const float* wq = Wq + (size_t)l * E_DIM * E_DIM;
        const float* wk = Wk + (size_t)l * E_DIM * E_DIM;
        const float* wv = Wv + (size_t)l * E_DIM * E_DIM;
        const float* wo = Wo + (size_t)l * E_DIM * E_DIM;
        const float* w1 = W1 + (size_t)l * E_DIM * F_DIM;
        const float* w2 = W2 + (size_t)l * F_DIM * E_DIM;

        ln_kernel<<<dim3(M_TOK), blk, 0, stream>>>(x, ln1w + l * E_DIM, ln1b + l * E_DIM, h);
        if (mid) {
            tconv_kernel<<<dim3(16, 16), blk, 0, stream>>>(wq, wqb, E_DIM, E_DIM);
            tconv_kernel<<<dim3(16, 16), blk, 0, stream>>>(wk, wkb, E_DIM, E_DIM);
            tconv_kernel<<<dim3(16, 16), blk, 0, stream>>>(wv, wvb, E_DIM, E_DIM);
            tconv_kernel<<<dim3(16, 16), blk, 0, stream>>>(wo, wob, E_DIM, E_DIM);
            tconv_kernel<<<dim3(64, 16), blk, 0, stream>>>(w1, w1b, E_DIM, F_DIM);
            tconv_kernel<<<dim3(16, 64), blk, 0, stream>>>(w2, w2b, F_DIM, E_DIM);

            gemm_qkv_bb_kernel<<<dim3(384), blk, 0, stream>>>(h, wqb, wkb, wvb,
                bq + l*E_DIM, bk + l*E_DIM, bv + l*E_DIM, qb, kb, vb);
            attn_mfma_kernel<<<dim3(512), blk, 0, stream>>>(qb, kb, vb, yb);
            gemm_bb_kernel<1><<<dim3(128), blk, 0, stream>>>(yb, wob, bo + l*E_DIM, x, x, nullptr, E_DIM, E_DIM, E_DIM);
            ln_kernel<<<dim3(M_TOK), blk, 0, stream>>>(x, ln2w + l * E_DIM, ln2b + l * E_DIM, h);
            gemm_bb_kernel<2><<<dim3(512), blk, 0, stream>>>(h, w1b, b1 + l*F_DIM, nullptr, nullptr, ub, F_DIM, E_DIM, F_DIM);
            gemm_bb_kernel<1><<<dim3(128), blk, 0, stream>>>(ub, w2b, b2 + l*E_DIM, x, x, nullptr, E_DIM, F_DIM, E_DIM);
        }
    }

    ln_kernel<<<dim3(M_TOK), blk, 0, stream>>>(x, lnfw, lnfb, h);
    if (big) {
        gemm_bb_kernel<3><<<dim3(6288), blk, 0, stream>>>(h, hdbM, nullptr, nullptr, out, nullptr, V_DIM, E_DIM, V_DIM);
    }
}

// Round 7
// 1173.374 us; speedup vs baseline: 9.9397x; 1.0490x over previous
//
#include <hip/hip_runtime.h>
#include <hip/hip_bf16.h>
#include <math.h>

#define E_DIM 1024
#define H_NUM 16
#define D_DIM 64
#define F_DIM 4096
#define L_NUM 4
#define B_NUM 2
#define S_LEN 1024
#define V_DIM 50257
#define M_TOK 2048   // B*S

typedef __attribute__((ext_vector_type(8))) short s8v;    // 8 bf16 (4 VGPRs)
typedef __attribute__((ext_vector_type(4))) float f4v;    // 4 fp32

static __device__ __forceinline__ float bf2f(unsigned short u) {
    union { unsigned int i; float f; } c; c.i = ((unsigned int)u) << 16; return c.f;
}
static __device__ __forceinline__ unsigned short f2bf(float f) {
    union { float f; unsigned int i; } c; c.f = f;
    unsigned int r = c.i + 0x7FFFu + ((c.i >> 16) & 1u);
    return (unsigned short)(r >> 16);
}

// async global->LDS, 16B per lane; dest is wave-uniform base + lane*16
static __device__ __forceinline__ void gload16(const ushort* g, ushort* l) {
    __builtin_amdgcn_global_load_lds(
        (const __attribute__((address_space(1))) unsigned int*)g,
        (__attribute__((address_space(3))) unsigned int*)l, 16, 0, 0);
}

// ---------------------------------------------------------------- embedding
__global__ void embed_kernel(const int* __restrict__ idx,
                             const float* __restrict__ tok,
                             const float* __restrict__ pos,
                             float* __restrict__ x) {
    int row = blockIdx.x;
    int s = row & (S_LEN - 1);
    int t = idx[row];
    const float* te = tok + (size_t)t * E_DIM;
    const float* pe = pos + (size_t)s * E_DIM;
    float* xr = x + (size_t)row * E_DIM;
    int c = threadIdx.x * 4;
    float4 a = *(const float4*)(te + c);
    float4 p = *(const float4*)(pe + c);
    float4 o; o.x = a.x + p.x; o.y = a.y + p.y; o.z = a.z + p.z; o.w = a.w + p.w;
    *(float4*)(xr + c) = o;
}

// ---------------------------------------------------------------- layernorm
__global__ void ln_kernel(const float* __restrict__ x,
                          const float* __restrict__ w,
                          const float* __restrict__ b,
                          ushort* __restrict__ out) {
    int row = blockIdx.x;
    const float* xr = x + (size_t)row * E_DIM;
    int tid = threadIdx.x;
    float4 v = *(const float4*)(xr + tid * 4);
    float s  = v.x + v.y + v.z + v.w;
    float s2 = v.x*v.x + v.y*v.y + v.z*v.z + v.w*v.w;
    #pragma unroll
    for (int m = 32; m >= 1; m >>= 1) {
        s  += __shfl_xor(s,  m, 64);
        s2 += __shfl_xor(s2, m, 64);
    }
    __shared__ float red[8];
    int wid = tid >> 6;
    if ((tid & 63) == 0) { red[wid] = s; red[wid + 4] = s2; }
    __syncthreads();
    s  = red[0] + red[1] + red[2] + red[3];
    s2 = red[4] + red[5] + red[6] + red[7];
    float mu  = s * (1.0f / E_DIM);
    float var = s2 * (1.0f / E_DIM) - mu * mu;
    float rs  = rsqrtf(var + 1e-5f);
    float4 wv = *(const float4*)(w + tid * 4);
    float4 bv = *(const float4*)(b + tid * 4);
    ushort4 o;
    o.x = f2bf((v.x - mu) * rs * wv.x + bv.x);
    o.y = f2bf((v.y - mu) * rs * wv.y + bv.y);
    o.z = f2bf((v.z - mu) * rs * wv.z + bv.z);
    o.w = f2bf((v.w - mu) * rs * wv.w + bv.w);
    *(ushort4*)(out + (size_t)row * E_DIM + tid * 4) = o;
}

// ---------------------------------------------------------------- weight prep
static __device__ __forceinline__ void tconv_body(
    const float* __restrict__ in, ushort* __restrict__ out, int K, int N, int bx, int by)
{
    __shared__ ushort t[64][72];
    int n0 = bx * 64, k0 = by * 64;
    int tid = threadIdx.x;
    int r = tid >> 4, c = (tid & 15) * 4;
    #pragma unroll
    for (int it = 0; it < 4; ++it) {
        int kl = it * 16 + r;
        float4 v = *(const float4*)(in + (size_t)(k0 + kl) * N + n0 + c);
        t[kl][c]   = f2bf(v.x); t[kl][c+1] = f2bf(v.y);
        t[kl][c+2] = f2bf(v.z); t[kl][c+3] = f2bf(v.w);
    }
    __syncthreads();
    int nl = tid >> 2, k8 = (tid & 3) * 16;
    s8v o0, o1;
    #pragma unroll
    for (int j = 0; j < 8; ++j) o0[j] = (short)t[k8 + j][nl];
    #pragma unroll
    for (int j = 0; j < 8; ++j) o1[j] = (short)t[k8 + 8 + j][nl];
    *(s8v*)(out + (size_t)(n0 + nl) * K + k0 + k8)     = o0;
    *(s8v*)(out + (size_t)(n0 + nl) * K + k0 + k8 + 8) = o1;
}

__global__ __launch_bounds__(256) void tconv_kernel(const float* __restrict__ in,
                                                    ushort* __restrict__ out, int K, int N) {
    tconv_body(in, out, K, N, blockIdx.x, blockIdx.y);
}

__global__ __launch_bounds__(256) void tconv_qkvo_all(
    const float* __restrict__ Wq, const float* __restrict__ Wk,
    const float* __restrict__ Wv, const float* __restrict__ Wo,
    ushort* __restrict__ out)
{
    int z = blockIdx.z, l = z >> 2, w = z & 3;
    const float* in = (w == 0 ? Wq : w == 1 ? Wk : w == 2 ? Wv : Wo)
                      + (size_t)l * E_DIM * E_DIM;
    tconv_body(in, out + (size_t)z * E_DIM * E_DIM, E_DIM, E_DIM, blockIdx.x, blockIdx.y);
}

__global__ __launch_bounds__(256) void tconv_w_all(
    const float* __restrict__ W, ushort* __restrict__ out, int K, int N)
{
    int l = blockIdx.z;
    tconv_body(W + (size_t)l * K * N, out + (size_t)l * K * N, K, N, blockIdx.x, blockIdx.y);
}

__global__ void conv_kernel(const float* __restrict__ in, ushort* __restrict__ out, int n) {
    int i = (blockIdx.x * 256 + threadIdx.x) * 8;
    if (i + 8 <= n) {
        float4 a = *(const float4*)(in + i);
        float4 b = *(const float4*)(in + i + 4);
        s8v o;
        o[0]=(short)f2bf(a.x); o[1]=(short)f2bf(a.y); o[2]=(short)f2bf(a.z); o[3]=(short)f2bf(a.w);
        o[4]=(short)f2bf(b.x); o[5]=(short)f2bf(b.y); o[6]=(short)f2bf(b.z); o[7]=(short)f2bf(b.w);
        *(s8v*)(out + i) = o;
    }
}

// ---------------------------------------------------------------- MFMA flash attention (split-KV)
// 512 blocks = 32 (b,h) x 16 q-tiles(64 rows). 8 waves: group 0 (waves 0-3) takes
// even KV tiles, group 1 odd tiles; each round stages 128 KV rows; groups keep
// private online-softmax state; merged once at the end via LDS.
#define KSTR 72
#define VSTR 144
__global__ __launch_bounds__(512, 4) void attn_mfma_kernel(
    const ushort* __restrict__ qg, const ushort* __restrict__ kg,
    const ushort* __restrict__ vg, ushort* __restrict__ yg)
{
    __shared__ ushort smem[27648];                       // 55296 B
    ushort (*Ks)[KSTR] = (ushort(*)[KSTR])smem;          // [128][72]
    ushort (*Vt)[VSTR] = (ushort(*)[VSTR])(smem + 128 * KSTR);          // [64][144]
    ushort (*Ps)[16][KSTR] = (ushort(*)[16][KSTR])(smem + 128 * KSTR + 64 * VSTR); // [8][16][72]
    float* mb = (float*)smem;                            // merge buf [4][64][25] (aliases Ks/Vt)

    int tid = threadIdx.x;
    int wid = tid >> 6, lane = tid & 63;
    int c = lane & 15, g = lane >> 4;
    int grp = wid >> 2, ws = wid & 3;

    int head = blockIdx.x & 31;
    int qt = 15 - (blockIdx.x >> 5);
    int b = head >> 4, h = head & 15;
    int qw = qt * 64 + ws * 16;
    size_t base = (size_t)b * S_LEN * E_DIM + (size_t)(h * D_DIM);

    s8v qf[2];
    #pragma unroll
    for (int ks = 0; ks < 2; ++ks)
        qf[ks] = *(const s8v*)(qg + base + (size_t)(qw + c) * E_DIM + ks * 32 + g * 8);

    f4v o[4];
    #pragma unroll
    for (int dt = 0; dt < 4; ++dt) o[dt] = (f4v){0.f, 0.f, 0.f, 0.f};
    float m[4], lsum[4];
    #pragma unroll
    for (int j = 0; j < 4; ++j) { m[j] = -1e30f; lsum[j] = 0.f; }

    int nr = (qt >> 1) + 1;
    for (int r = 0; r < nr; ++r) {
        int t0 = r * 128;
        // ---- stage 128 K rows [t][d] and V^T [d][t] (block-XOR swizzled), 512 threads
        #pragma unroll
        for (int it = 0; it < 2; ++it) {
            int ch = tid + it * 512;                  // 0..1023
            int tr = ch >> 3, dc = (ch & 7) << 3;     // tr 0..127, dc 0..56
            s8v kv = *(const s8v*)(kg + base + (size_t)(t0 + tr) * E_DIM + dc);
            *(s8v*)(&Ks[tr][dc]) = kv;
            s8v vv = *(const s8v*)(vg + base + (size_t)(t0 + tr) * E_DIM + dc);
            int tsw = tr ^ dc;                        // dc = (d>>3)<<3, XOR on t bits 3-5
            #pragma unroll
            for (int j = 0; j < 8; ++j)
                Vt[dc + j][tsw] = (ushort)vv[j];
        }
        __syncthreads();

        int myt = r * 2 + grp;                        // this group's tile
        if (myt <= qt) {
            int toff = grp * 64;
            // ---- S = Q K^T
            f4v s4[4];
            #pragma unroll
            for (int tj = 0; tj < 4; ++tj) {
                s4[tj] = (f4v){0.f, 0.f, 0.f, 0.f};
                #pragma unroll
                for (int ks = 0; ks < 2; ++ks) {
                    s8v kf = *(const s8v*)(&Ks[toff + tj * 16 + c][ks * 32 + g * 8]);
                    s4[tj] = __builtin_amdgcn_mfma_f32_16x16x32_bf16(qf[ks], kf, s4[tj], 0, 0, 0);
                }
            }

            bool diag = (myt == qt);
            float sc[4][4], pm[4];
            #pragma unroll
            for (int j = 0; j < 4; ++j) pm[j] = -1e30f;
            #pragma unroll
            for (int tj = 0; tj < 4; ++tj)
                #pragma unroll
                for (int j = 0; j < 4; ++j) {
                    float val = s4[tj][j] * 0.125f;
                    if (diag) {
                        int t_loc = tj * 16 + c;
                        int q_loc = ws * 16 + 4 * g + j;
                        if (t_loc > q_loc) val = -1e30f;
                    }
                    sc[tj][j] = val;
                    pm[j] = fmaxf(pm[j], val);
                }
            #pragma unroll
            for (int msk = 1; msk <= 8; msk <<= 1)
                #pragma unroll
                for (int j = 0; j < 4; ++j)
                    pm[j] = fmaxf(pm[j], __shfl_xor(pm[j], msk, 64));
            float rs[4], corr[4];
            #pragma unroll
            for (int j = 0; j < 4; ++j) {
                float nm = fmaxf(m[j], pm[j]);
                corr[j] = __expf(m[j] - nm);
                m[j] = nm;
                rs[j] = 0.f;
            }
            #pragma unroll
            for (int tj = 0; tj < 4; ++tj)
                #pragma unroll
                for (int j = 0; j < 4; ++j) {
                    float p = __expf(sc[tj][j] - m[j]);
                    rs[j] += p;
                    Ps[wid][4 * g + j][(tj * 16 + c) ^ (g << 3)] = f2bf(p);
                }
            #pragma unroll
            for (int msk = 1; msk <= 8; msk <<= 1)
                #pragma unroll
                for (int j = 0; j < 4; ++j)
                    rs[j] += __shfl_xor(rs[j], msk, 64);
            #pragma unroll
            for (int j = 0; j < 4; ++j) lsum[j] = lsum[j] * corr[j] + rs[j];
            #pragma unroll
            for (int dt = 0; dt < 4; ++dt)
                #pragma unroll
                for (int j = 0; j < 4; ++j) o[dt][j] *= corr[j];

            // ---- O += P V
            #pragma unroll
            for (int ks = 0; ks < 2; ++ks) {
                int blk = g + 4 * ks;                 // local t-block 0..7
                int pblk = blk ^ (c >> 2);
                s8v pa = *(const s8v*)(&Ps[wid][c][pblk << 3]);
                int tb = grp * 8 + blk;               // global t-block 0..15
                #pragma unroll
                for (int dt = 0; dt < 4; ++dt) {
                    int d = dt * 16 + c;
                    int vblk = tb ^ ((d >> 3) & 7);
                    s8v vb = *(const s8v*)(&Vt[d][vblk << 3]);
                    o[dt] = __builtin_amdgcn_mfma_f32_16x16x32_bf16(pa, vb, o[dt], 0, 0, 0);
                }
            }
        }
        __syncthreads();
    }

    // ---- merge group 1 into group 0 (LDS, stride 25 -> conflict-free)
    if (grp == 1) {
        float* dst = mb + (ws * 64 + lane) * 25;
        #pragma unroll
        for (int j = 0; j < 4; ++j) { dst[j] = m[j]; dst[4 + j] = lsum[j]; }
        #pragma unroll
        for (int dt = 0; dt < 4; ++dt)
            #pragma unroll
            for (int j = 0; j < 4; ++j) dst[8 + dt * 4 + j] = o[dt][j];
    }
    __syncthreads();
    if (grp == 0) {
        const float* src = mb + (ws * 64 + lane) * 25;
        float sA[4], sB[4];
        #pragma unroll
        for (int j = 0; j < 4; ++j) {
            float mB = src[j], lB = src[4 + j];
            float mN = fmaxf(m[j], mB);
            sA[j] = __expf(m[j] - mN);
            sB[j] = __expf(mB - mN);
            lsum[j] = lsum[j] * sA[j] + lB * sB[j];
        }
        float inv[4];
        #pragma unroll
        for (int j = 0; j < 4; ++j) inv[j] = 1.f / lsum[j];
        #pragma unroll
        for (int dt = 0; dt < 4; ++dt)
            #pragma unroll
            for (int j = 0; j < 4; ++j) {
                float ov = o[dt][j] * sA[j] + src[8 + dt * 4 + j] * sB[j];
                yg[base + (size_t)(qw + 4 * g + j) * E_DIM + dt * 16 + c] = f2bf(ov * inv[j]);
            }
    }
}

// ---------------------------------------------------------------- bf16 GEMM 128x128 (proven)
template<int EPI>
static __device__ __forceinline__ void gemm_bb_body(
    const ushort* __restrict__ A, const ushort* __restrict__ B,
    const float* __restrict__ bias, const float* __restrict__ res,
    float* __restrict__ outF, ushort* __restrict__ outB,
    int Ndim, int Kdim, int m0, int n0, int nRows)
{
    __shared__ ushort As[128 * 64];
    __shared__ ushort Bs[128 * 64];
    int tid = threadIdx.x;
    int wid = tid >> 6, lane = tid & 63;
    int wr = wid >> 1, wc = wid & 1;
    int fr = lane & 15, fq = lane >> 4;
    int lr = lane >> 3, ls = lane & 7;

    f4v acc[4][4];
    #pragma unroll
    for (int mi = 0; mi < 4; ++mi)
        #pragma unroll
        for (int ni = 0; ni < 4; ++ni)
            acc[mi][ni] = (f4v){0.f, 0.f, 0.f, 0.f};

    for (int k0 = 0; k0 < Kdim; k0 += 64) {
        #pragma unroll
        for (int it = 0; it < 4; ++it) {
            int r = wid * 32 + it * 8 + lr;
            int ss = ls ^ (r & 7);
            gload16(A + (size_t)(m0 + r) * Kdim + k0 + ss * 8,
                    As + r * 64 - lr * 64 - ls * 8);
        }
        #pragma unroll
        for (int it = 0; it < 4; ++it) {
            int r = wid * 32 + it * 8 + lr;
            int ss = ls ^ (r & 7);
            int br = n0 + r; if (br >= nRows) br = nRows - 1;
            gload16(B + (size_t)br * Kdim + k0 + ss * 8,
                    Bs + r * 64 - lr * 64 - ls * 8);
        }
        __syncthreads();
        #pragma unroll
        for (int ks = 0; ks < 2; ++ks) {
            s8v af[4], bfv[4];
            #pragma unroll
            for (int mi = 0; mi < 4; ++mi) {
                int Ra = wr * 64 + mi * 16 + fr;
                int Sa = (ks * 4 + fq) ^ (fr & 7);
                af[mi] = *(const s8v*)(As + Ra * 64 + Sa * 8);
            }
            #pragma unroll
            for (int ni = 0; ni < 4; ++ni) {
                int Rb = wc * 64 + ni * 16 + fr;
                int Sb = (ks * 4 + fq) ^ (fr & 7);
                bfv[ni] = *(const s8v*)(Bs + Rb * 64 + Sb * 8);
            }
            #pragma unroll
            for (int mi = 0; mi < 4; ++mi)
                #pragma unroll
                for (int ni = 0; ni < 4; ++ni)
                    acc[mi][ni] = __builtin_amdgcn_mfma_f32_16x16x32_bf16(
                        af[mi], bfv[ni], acc[mi][ni], 0, 0, 0);
        }
        __syncthreads();
    }

    #pragma unroll
    for (int mi = 0; mi < 4; ++mi) {
        int row = m0 + wr * 64 + mi * 16 + fq * 4;
        #pragma unroll
        for (int ni = 0; ni < 4; ++ni) {
            int col = n0 + wc * 64 + ni * 16 + fr;
            float bv = 0.f;
            if (EPI == 0 || EPI == 1 || EPI == 2) bv = bias[col];
            #pragma unroll
            for (int j = 0; j < 4; ++j) {
                float val = acc[mi][ni][j] + bv;
                size_t off = (size_t)(row + j) * Ndim + col;
                if (EPI == 0) {
                    outB[off] = f2bf(val);
                } else if (EPI == 1) {
                    outF[off] = res[off] + val;
                } else if (EPI == 2) {
                    val = 0.5f * val * (1.f + erff(val * 0.70710678118654752f));
                    outB[off] = f2bf(val);
                } else {
                    if (col < Ndim) outF[off] = val;
                }
            }
        }
    }
}

template<int EPI>
__global__ __launch_bounds__(256) void gemm_bb_kernel(
    const ushort* __restrict__ A, const ushort* __restrict__ B,
    const float* __restrict__ bias, const float* __restrict__ res,
    float* __restrict__ outF, ushort* __restrict__ outB,
    int Ndim, int Kdim, int nRows)
{
    int x = blockIdx.x & 7, i = blockIdx.x >> 3;
    int mb = x * 2 + (i & 1), nb = i >> 1;
    gemm_bb_body<EPI>(A, B, bias, res, outF, outB, Ndim, Kdim, mb * 128, nb * 128, nRows);
}

__global__ __launch_bounds__(256) void gemm_qkv_bb_kernel(
    const ushort* __restrict__ A,
    const ushort* __restrict__ Bq, const ushort* __restrict__ Bk, const ushort* __restrict__ Bv,
    const float* __restrict__ bq, const float* __restrict__ bk, const float* __restrict__ bv,
    ushort* __restrict__ oq, ushort* __restrict__ ok, ushort* __restrict__ ov)
{
    int x = blockIdx.x & 7, i = blockIdx.x >> 3;
    int sel = i >> 4, j = i & 15;
    int mb = x * 2 + (j & 1), nb = j >> 1;
    const ushort* B   = (sel == 0) ? Bq : (sel == 1) ? Bk : Bv;
    const float* bias = (sel == 0) ? bq : (sel == 1) ? bk : bv;
    ushort* o         = (sel == 0) ? oq : (sel == 1) ? ok : ov;
    gemm_bb_body<0>(A, B, bias, nullptr, nullptr, o, E_DIM, E_DIM, mb * 128, nb * 128, E_DIM);
}

// ---------------------------------------------------------------- bf16 GEMM 64x128
template<int EPI>
static __device__ __forceinline__ void gemm64_body(
    const ushort* __restrict__ A, const ushort* __restrict__ B,
    const float* __restrict__ bias, const float* __restrict__ res,
    float* __restrict__ outF, ushort* __restrict__ outB,
    int Ndim, int Kdim, int m0, int n0)
{
    __shared__ ushort As[64 * 64];
    __shared__ ushort Bs[128 * 64];
    int tid = threadIdx.x;
    int wid = tid >> 6, lane = tid & 63;
    int fr = lane & 15, fq = lane >> 4;
    int lr = lane >> 3, ls = lane & 7;

    f4v acc[4][2];
    #pragma unroll
    for (int mi = 0; mi < 4; ++mi)
        #pragma unroll
        for (int ni = 0; ni < 2; ++ni)
            acc[mi][ni] = (f4v){0.f, 0.f, 0.f, 0.f};

    for (int k0 = 0; k0 < Kdim; k0 += 64) {
        #pragma unroll
        for (int it = 0; it < 2; ++it) {
            int r = wid * 16 + it * 8 + lr;
            int ss = ls ^ (r & 7);
            gload16(A + (size_t)(m0 + r) * Kdim + k0 + ss * 8,
                    As + r * 64 - lr * 64 - ls * 8);
        }
        #pragma unroll
        for (int it = 0; it < 4; ++it) {
            int r = wid * 32 + it * 8 + lr;
            int ss = ls ^ (r & 7);
            gload16(B + (size_t)(n0 + r) * Kdim + k0 + ss * 8,
                    Bs + r * 64 - lr * 64 - ls * 8);
        }
        __syncthreads();
        #pragma unroll
        for (int ks = 0; ks < 2; ++ks) {
            s8v af[4], bfv[2];
            #pragma unroll
            for (int mi = 0; mi < 4; ++mi) {
                int Ra = mi * 16 + fr;
                int Sa = (ks * 4 + fq) ^ (fr & 7);
                af[mi] = *(const s8v*)(As + Ra * 64 + Sa * 8);
            }
            #pragma unroll
            for (int ni = 0; ni < 2; ++ni) {
                int Rb = wid * 32 + ni * 16 + fr;
                int Sb = (ks * 4 + fq) ^ (fr & 7);
                bfv[ni] = *(const s8v*)(Bs + Rb * 64 + Sb * 8);
            }
            #pragma unroll
            for (int mi = 0; mi < 4; ++mi)
                #pragma unroll
                for (int ni = 0; ni < 2; ++ni)
                    acc[mi][ni] = __builtin_amdgcn_mfma_f32_16x16x32_bf16(
                        af[mi], bfv[ni], acc[mi][ni], 0, 0, 0);
        }
        __syncthreads();
    }

    #pragma unroll
    for (int mi = 0; mi < 4; ++mi) {
        int row = m0 + mi * 16 + fq * 4;
        #pragma unroll
        for (int ni = 0; ni < 2; ++ni) {
            int col = n0 + wid * 32 + ni * 16 + fr;
            float bv = bias[col];
            #pragma unroll
            for (int j = 0; j < 4; ++j) {
                float val = acc[mi][ni][j] + bv;
                size_t off = (size_t)(row + j) * Ndim + col;
                if (EPI == 0) {
                    outB[off] = f2bf(val);
                } else {
                    outF[off] = res[off] + val;
                }
            }
        }
    }
}

template<int EPI>
__global__ __launch_bounds__(256) void gemm64_kernel(
    const ushort* __restrict__ A, const ushort* __restrict__ B,
    const float* __restrict__ bias, const float* __restrict__ res,
    float* __restrict__ outF, ushort* __restrict__ outB,
    int Ndim, int Kdim)
{
    int x = blockIdx.x & 7, i = blockIdx.x >> 3;
    int mb = x * 4 + (i & 3), nb = i >> 2;
    gemm64_body<EPI>(A, B, bias, res, outF, outB, Ndim, Kdim, mb * 64, nb * 128);
}

__global__ __launch_bounds__(256) void gemm64_qkv_kernel(
    const ushort* __restrict__ A, const ushort* __restrict__ Wall,
    const float* __restrict__ bq, const float* __restrict__ bk, const float* __restrict__ bv,
    ushort* __restrict__ oq, ushort* __restrict__ ok, ushort* __restrict__ ov)
{
    int x = blockIdx.x & 7, i = blockIdx.x >> 3;
    int sel = i >> 5, j = i & 31;
    int mb = x * 4 + (j & 3), nb = j >> 2;
    const ushort* B   = Wall + (size_t)sel * E_DIM * E_DIM;
    const float* bias = (sel == 0) ? bq : (sel == 1) ? bk : bv;
    ushort* o         = (sel == 0) ? oq : (sel == 1) ? ok : ov;
    gemm64_body<0>(A, B, bias, nullptr, nullptr, o, E_DIM, E_DIM, mb * 64, nb * 128);
}

// ---------------------------------------------------------------- launch
extern "C" void kernel_launch(void* const* d_in, const int* in_sizes, int n_in,
                              void* d_out, int out_size, void* d_ws, size_t ws_size,
                              hipStream_t stream) {
    (void)in_sizes; (void)n_in; (void)out_size;
    const int*   idx  = (const int*)d_in[0];
    const float* tok  = (const float*)d_in[1];
    const float* pos  = (const float*)d_in[2];
    const float* ln1w = (const float*)d_in[3];
    const float* ln1b = (const float*)d_in[4];
    const float* Wq   = (const float*)d_in[5];
    const float* bq   = (const float*)d_in[6];
    const float* Wk   = (const float*)d_in[7];
    const float* bk   = (const float*)d_in[8];
    const float* Wv   = (const float*)d_in[9];
    const float* bv   = (const float*)d_in[10];
    const float* Wo   = (const float*)d_in[11];
    const float* bo   = (const float*)d_in[12];
    const float* ln2w = (const float*)d_in[13];
    const float* ln2b = (const float*)d_in[14];
    const float* W1   = (const float*)d_in[15];
    const float* b1   = (const float*)d_in[16];
    const float* W2   = (const float*)d_in[17];
    const float* b2   = (const float*)d_in[18];
    const float* lnfw = (const float*)d_in[19];
    const float* lnfb = (const float*)d_in[20];
    const float* headW= (const float*)d_in[21];
    float* out = (float*)d_out;

    char* ws = (char*)d_ws;
    float*  x  = (float*)(ws);                              // 8 MB
    ushort* h  = (ushort*)(ws + 8u  * 1024 * 1024);         // 4 MB
    ushort* qb = (ushort*)(ws + 12u * 1024 * 1024);
    ushort* kb = (ushort*)(ws + 16u * 1024 * 1024);
    ushort* vb = (ushort*)(ws + 20u * 1024 * 1024);
    ushort* yb = (ushort*)(ws + 24u * 1024 * 1024);
    ushort* ub = (ushort*)(ws + 28u * 1024 * 1024);         // 16 MB
    // mid tier: per-layer reuse buffers
    ushort* wqb = (ushort*)(ws + 44u * 1024 * 1024);
    ushort* wkb = (ushort*)(ws + 46u * 1024 * 1024);
    ushort* wvb = (ushort*)(ws + 48u * 1024 * 1024);
    ushort* wob = (ushort*)(ws + 50u * 1024 * 1024);
    ushort* w1b = (ushort*)(ws + 52u * 1024 * 1024);
    ushort* w2b = (ushort*)(ws + 60u * 1024 * 1024);
    ushort* hdbM = (ushort*)(ws + 68u * 1024 * 1024);       // mid-tier head (98.2 MB)
    // huge tier: all weights upfront
    ushort* wall  = (ushort*)(ws + 44u  * 1024 * 1024);     // 32 MB
    ushort* w1all = (ushort*)(ws + 76u  * 1024 * 1024);     // 32 MB
    ushort* w2all = (ushort*)(ws + 108u * 1024 * 1024);     // 32 MB
    ushort* hdbH  = (ushort*)(ws + 140u * 1024 * 1024);     // 98.2 MB

    size_t headB = (size_t)V_DIM * E_DIM * 2;
    bool huge = ws_size >= 140ull * 1024 * 1024 + headB;
    bool big  = ws_size >= 68ull * 1024 * 1024 + headB;
    bool mid  = ws_size >= 68ull * 1024 * 1024;

    dim3 blk(256);
    dim3 blkA(512);
    embed_kernel<<<dim3(M_TOK), blk, 0, stream>>>(idx, tok, pos, x);

    if (huge) {
        tconv_qkvo_all<<<dim3(16, 16, 16), blk, 0, stream>>>(Wq, Wk, Wv, Wo, wall);
        tconv_w_all<<<dim3(64, 16, 4), blk, 0, stream>>>(W1, w1all, E_DIM, F_DIM);
        tconv_w_all<<<dim3(16, 64, 4), blk, 0, stream>>>(W2, w2all, F_DIM, E_DIM);
        int n = V_DIM * E_DIM;
        conv_kernel<<<dim3((n / 8 + 255) / 256), blk, 0, stream>>>(headW, hdbH, n);

        for (int l = 0; l < L_NUM; ++l) {
            const ushort* wl  = wall  + (size_t)(l * 4) * E_DIM * E_DIM;
            const ushort* wol = wall  + (size_t)(l * 4 + 3) * E_DIM * E_DIM;
            const ushort* w1l = w1all + (size_t)l * E_DIM * F_DIM;
            const ushort* w2l = w2all + (size_t)l * F_DIM * E_DIM;

            ln_kernel<<<dim3(M_TOK), blk, 0, stream>>>(x, ln1w + l * E_DIM, ln1b + l * E_DIM, h);
            gemm64_qkv_kernel<<<dim3(768), blk, 0, stream>>>(h, wl,
                bq + l*E_DIM, bk + l*E_DIM, bv + l*E_DIM, qb, kb, vb);
            attn_mfma_kernel<<<dim3(512), blkA, 0, stream>>>(qb, kb, vb, yb);
            gemm64_kernel<1><<<dim3(256), blk, 0, stream>>>(yb, wol, bo + l*E_DIM, x, x, nullptr, E_DIM, E_DIM);
            ln_kernel<<<dim3(M_TOK), blk, 0, stream>>>(x, ln2w + l * E_DIM, ln2b + l * E_DIM, h);
            gemm_bb_kernel<2><<<dim3(512), blk, 0, stream>>>(h, w1l, b1 + l*F_DIM, nullptr, nullptr, ub, F_DIM, E_DIM, F_DIM);
            gemm64_kernel<1><<<dim3(256), blk, 0, stream>>>(ub, w2l, b2 + l*E_DIM, x, x, nullptr, E_DIM, F_DIM);
        }
        ln_kernel<<<dim3(M_TOK), blk, 0, stream>>>(x, lnfw, lnfb, h);
        gemm_bb_kernel<3><<<dim3(6288), blk, 0, stream>>>(h, hdbH, nullptr, nullptr, out, nullptr, V_DIM, E_DIM, V_DIM);
        return;
    }

    if (big) {
        int n = V_DIM * E_DIM;
        conv_kernel<<<dim3((n / 8 + 255) / 256), blk, 0, stream>>>(headW, hdbM, n);
    }

    for (int l = 0; l < L_NUM; ++l) {
        const float* wq = Wq + (size_t)l * E_DIM * E_DIM;
        const float* wk = Wk + (size_t)l * E_DIM * E_DIM;
        const float* wv = Wv + (size_t)l * E_DIM * E_DIM;
        const float* wo = Wo + (size_t)l * E_DIM * E_DIM;
        const float* w1 = W1 + (size_t)l * E_DIM * F_DIM;
        const float* w2 = W2 + (size_t)l * F_DIM * E_DIM;

        ln_kernel<<<dim3(M_TOK), blk, 0, stream>>>(x, ln1w + l * E_DIM, ln1b + l * E_DIM, h);
        if (mid) {
            tconv_kernel<<<dim3(16, 16), blk, 0, stream>>>(wq, wqb, E_DIM, E_DIM);
            tconv_kernel<<<dim3(16, 16), blk, 0, stream>>>(wk, wkb, E_DIM, E_DIM);
            tconv_kernel<<<dim3(16, 16), blk, 0, stream>>>(wv, wvb, E_DIM, E_DIM);
            tconv_kernel<<<dim3(16, 16), blk, 0, stream>>>(wo, wob, E_DIM, E_DIM);
            tconv_kernel<<<dim3(64, 16), blk, 0, stream>>>(w1, w1b, E_DIM, F_DIM);
            tconv_kernel<<<dim3(16, 64), blk, 0, stream>>>(w2, w2b, F_DIM, E_DIM);

            gemm_qkv_bb_kernel<<<dim3(384), blk, 0, stream>>>(h, wqb, wkb, wvb,
                bq + l*E_DIM, bk + l*E_DIM, bv + l*E_DIM, qb, kb, vb);
            attn_mfma_kernel<<<dim3(512), blkA, 0, stream>>>(qb, kb, vb, yb);
            gemm_bb_kernel<1><<<dim3(128), blk, 0, stream>>>(yb, wob, bo + l*E_DIM, x, x, nullptr, E_DIM, E_DIM, E_DIM);
            ln_kernel<<<dim3(M_TOK), blk, 0, stream>>>(x, ln2w + l * E_DIM, ln2b + l * E_DIM, h);
            gemm_bb_kernel<2><<<dim3(512), blk, 0, stream>>>(h, w1b, b1 + l*F_DIM, nullptr, nullptr, ub, F_DIM, E_DIM, F_DIM);
            gemm_bb_kernel<1><<<dim3(128), blk, 0, stream>>>(ub, w2b, b2 + l*E_DIM, x, x, nullptr, E_DIM, F_DIM, E_DIM);
        }
    }

    ln_kernel<<<dim3(M_TOK), blk, 0, stream>>>(x, lnfw, lnfb, h);
    if (big) {
        gemm_bb_kernel<3><<<dim3(6288), blk, 0, stream>>>(h, hdbM, nullptr, nullptr, out, nullptr, V_DIM, E_DIM, V_DIM);
    }
}